// Round 1
// baseline (538.551 us; speedup 1.0000x reference)
//
#include <hip/hip_runtime.h>
#include <hip/hip_bf16.h>

#define EPS 1e-5f

// ---------------------------------------------------------------- degree/CSR

__global__ void count_kernel(const int* __restrict__ dst, int* __restrict__ counts, int e) {
    int i = blockIdx.x * blockDim.x + threadIdx.x;
    if (i < e) atomicAdd(&counts[dst[i]], 1);
}

__global__ void dinv_kernel(const int* __restrict__ counts, float* __restrict__ dinv, int n) {
    int i = blockIdx.x * blockDim.x + threadIdx.x;
    if (i < n) dinv[i] = rsqrtf((float)(counts[i] + 1));  // +1 self loop
}

// single-block exclusive scan over counts[n] -> offs[n+1]
__global__ __launch_bounds__(1024) void scan_kernel(const int* __restrict__ counts,
                                                    int* __restrict__ offs, int n) {
    __shared__ int sh[1024];
    int t = threadIdx.x;
    int per = (n + 1023) / 1024;
    int lo = t * per;
    int hi = lo + per; if (hi > n) hi = n;
    int s = 0;
    for (int i = lo; i < hi; ++i) s += counts[i];
    sh[t] = s;
    __syncthreads();
    for (int d = 1; d < 1024; d <<= 1) {
        int v = (t >= d) ? sh[t - d] : 0;
        __syncthreads();
        sh[t] += v;
        __syncthreads();
    }
    int run = (t == 0) ? 0 : sh[t - 1];
    for (int i = lo; i < hi; ++i) { offs[i] = run; run += counts[i]; }
    if (t == 1023) offs[n] = sh[1023];
}

__global__ void scatter_kernel(const int* __restrict__ src, const int* __restrict__ dst,
                               const int* __restrict__ offs, int* __restrict__ fill,
                               const float* __restrict__ dinv,
                               int* __restrict__ csr_col, float* __restrict__ csr_val, int e) {
    int i = blockIdx.x * blockDim.x + threadIdx.x;
    if (i >= e) return;
    int s = src[i], d = dst[i];
    int pos = offs[d] + atomicAdd(&fill[d], 1);
    csr_col[pos] = s;
    csr_val[pos] = dinv[s] * dinv[d];
}

// ---------------------------------------------------------------- GEMMs (fp32)

// C[n,128] = A[n,128] @ W[128,128]; W fully in LDS; 64 rows/block, 8x4 per thread
__global__ __launch_bounds__(256) void gemm128_kernel(const float* __restrict__ A,
                                                      const float* __restrict__ W,
                                                      float* __restrict__ C, int n) {
    __shared__ float Wl[128 * 128];
    int tid = threadIdx.x;
    const float4* Wv = (const float4*)W;
    float4* Wlv = (float4*)Wl;
#pragma unroll
    for (int i = 0; i < 16; ++i) Wlv[tid + 256 * i] = Wv[tid + 256 * i];
    __syncthreads();

    int ty = tid >> 5, tx = tid & 31;
    int row0 = blockIdx.x * 64 + ty * 8;
    int cb = tx * 4;
    const float* Ap[8];
#pragma unroll
    for (int r = 0; r < 8; ++r) {
        int rr = row0 + r; if (rr > n - 1) rr = n - 1;
        Ap[r] = A + (size_t)rr * 128;
    }
    float acc[8][4] = {};
    for (int k = 0; k < 128; k += 4) {
        float wk[4][4];
#pragma unroll
        for (int i = 0; i < 4; ++i)
            *(float4*)wk[i] = *(const float4*)&Wl[(k + i) * 128 + cb];
#pragma unroll
        for (int r = 0; r < 8; ++r) {
            float av[4];
            *(float4*)av = *(const float4*)(Ap[r] + k);
#pragma unroll
            for (int i = 0; i < 4; ++i)
#pragma unroll
                for (int j = 0; j < 4; ++j)
                    acc[r][j] = fmaf(av[i], wk[i][j], acc[r][j]);
        }
    }
#pragma unroll
    for (int r = 0; r < 8; ++r) {
        int rr = row0 + r;
        if (rr < n)
            *(float4*)&C[(size_t)rr * 128 + cb] =
                make_float4(acc[r][0], acc[r][1], acc[r][2], acc[r][3]);
    }
}

// C[n,40] = A[n,128] @ W[128,40]; W zero-padded to 64 cols in LDS; 64 rows/block
__global__ __launch_bounds__(256) void gemm40_kernel(const float* __restrict__ A,
                                                     const float* __restrict__ W,
                                                     float* __restrict__ C, int n) {
    __shared__ float Wl[128 * 64];
    int tid = threadIdx.x;
    for (int idx = tid; idx < 128 * 64; idx += 256) {
        int r = idx >> 6, c = idx & 63;
        Wl[idx] = (c < 40) ? W[r * 40 + c] : 0.0f;
    }
    __syncthreads();

    int ty = tid >> 4, tx = tid & 15;       // 16x16 threads
    int row0 = blockIdx.x * 64 + ty * 4;
    int cb = tx * 4;
    const float* Ap[4];
#pragma unroll
    for (int r = 0; r < 4; ++r) {
        int rr = row0 + r; if (rr > n - 1) rr = n - 1;
        Ap[r] = A + (size_t)rr * 128;
    }
    float acc[4][4] = {};
    for (int k = 0; k < 128; k += 4) {
        float wk[4][4];
#pragma unroll
        for (int i = 0; i < 4; ++i)
            *(float4*)wk[i] = *(const float4*)&Wl[(k + i) * 64 + cb];
#pragma unroll
        for (int r = 0; r < 4; ++r) {
            float av[4];
            *(float4*)av = *(const float4*)(Ap[r] + k);
#pragma unroll
            for (int i = 0; i < 4; ++i)
#pragma unroll
                for (int j = 0; j < 4; ++j)
                    acc[r][j] = fmaf(av[i], wk[i][j], acc[r][j]);
        }
    }
    if (cb < 40) {
#pragma unroll
        for (int r = 0; r < 4; ++r) {
            int rr = row0 + r;
            if (rr < n)
                *(float4*)&C[(size_t)rr * 40 + cb] =
                    make_float4(acc[r][0], acc[r][1], acc[r][2], acc[r][3]);
        }
    }
}

// ---------------------------------------------------------------- aggregation

// out[node,:] = dinv[node]^2 * H[node,:] + sum_e vals[e]*H[cols[e],:]
// one 64-lane wave per node, float2 per lane (128 features)
__global__ __launch_bounds__(256) void aggregate128_kernel(
    const float* __restrict__ H, const int* __restrict__ offs,
    const int* __restrict__ cols, const float* __restrict__ vals,
    const float* __restrict__ dinv, float* __restrict__ out, int n) {
    int node = (blockIdx.x * blockDim.x + threadIdx.x) >> 6;
    if (node >= n) return;
    int lane = threadIdx.x & 63;
    float di = dinv[node];
    float2 h0 = *(const float2*)(H + (size_t)node * 128 + lane * 2);
    float2 acc;
    acc.x = h0.x * di * di;
    acc.y = h0.y * di * di;
    int e0 = offs[node], e1 = offs[node + 1];
    for (int e = e0; e < e1; ++e) {
        int s = cols[e];
        float w = vals[e];
        float2 hv = *(const float2*)(H + (size_t)s * 128 + lane * 2);
        acc.x += hv.x * w;
        acc.y += hv.y * w;
    }
    *(float2*)(out + (size_t)node * 128 + lane * 2) = acc;
}

// final layer: aggregate 40-wide + bias + log_softmax, one wave per node
__global__ __launch_bounds__(256) void agg40_lsm_kernel(
    const float* __restrict__ H, const int* __restrict__ offs,
    const int* __restrict__ cols, const float* __restrict__ vals,
    const float* __restrict__ dinv, const float* __restrict__ b3,
    float* __restrict__ out, int n) {
    int node = (blockIdx.x * blockDim.x + threadIdx.x) >> 6;
    if (node >= n) return;
    int lane = threadIdx.x & 63;
    bool active = lane < 40;
    float di = dinv[node];
    float acc = 0.0f;
    if (active) acc = H[(size_t)node * 40 + lane] * di * di;
    int e0 = offs[node], e1 = offs[node + 1];
    for (int e = e0; e < e1; ++e) {
        int s = cols[e];
        float w = vals[e];
        if (active) acc += H[(size_t)s * 40 + lane] * w;
    }
    float v = active ? acc + b3[lane] : -1e30f;
    float m = v;
#pragma unroll
    for (int off = 32; off; off >>= 1) m = fmaxf(m, __shfl_xor(m, off));
    float ex = active ? expf(v - m) : 0.0f;
    float s = ex;
#pragma unroll
    for (int off = 32; off; off >>= 1) s += __shfl_xor(s, off);
    if (active) out[(size_t)node * 40 + lane] = v - m - logf(s);
}

// ---------------------------------------------------------------- batchnorm

// stats[c] = sum, stats[128+c] = sumsq  (atomic accumulation; pre-zeroed)
__global__ __launch_bounds__(256) void bn_stats_kernel(const float* __restrict__ X,
                                                       float* __restrict__ stats, int n) {
    int tid = threadIdx.x;
    int c = tid & 127;
    int r0 = blockIdx.x * 2 + (tid >> 7);
    float s = 0.0f, q = 0.0f;
    for (int r = r0; r < n; r += gridDim.x * 2) {
        float v = X[(size_t)r * 128 + c];
        s += v;
        q += v * v;
    }
    __shared__ float sh[256], shq[256];
    sh[tid] = s; shq[tid] = q;
    __syncthreads();
    if (tid < 128) {
        atomicAdd(&stats[c], sh[tid] + sh[tid + 128]);
        atomicAdd(&stats[128 + c], shq[tid] + shq[tid + 128]);
    }
}

__global__ void bn_apply_relu_kernel(const float* __restrict__ X,
                                     const float* __restrict__ stats,
                                     const float* __restrict__ gamma,
                                     const float* __restrict__ beta,
                                     float* __restrict__ Y, int n, float invn) {
    int i = blockIdx.x * blockDim.x + threadIdx.x;
    int total = n * 32;  // float4s
    if (i >= total) return;
    int c0 = (i & 31) * 4;
    float4 x = ((const float4*)X)[i];
    float xv[4] = {x.x, x.y, x.z, x.w};
    float o[4];
#pragma unroll
    for (int j = 0; j < 4; ++j) {
        int c = c0 + j;
        float mu = stats[c] * invn;
        float var = stats[128 + c] * invn - mu * mu;
        float sc = gamma[c] * rsqrtf(var + EPS);
        float sh = beta[c] - mu * sc;
        float v = fmaf(xv[j], sc, sh);
        o[j] = v > 0.0f ? v : 0.0f;
    }
    ((float4*)Y)[i] = make_float4(o[0], o[1], o[2], o[3]);
}

// ---------------------------------------------------------------- launch

extern "C" void kernel_launch(void* const* d_in, const int* in_sizes, int n_in,
                              void* d_out, int out_size, void* d_ws, size_t ws_size,
                              hipStream_t stream) {
    const float* x   = (const float*)d_in[0];
    const int*   ei  = (const int*)d_in[1];
    const float* W1  = (const float*)d_in[2];
    const float* g1  = (const float*)d_in[4];
    const float* bt1 = (const float*)d_in[5];
    const float* W2  = (const float*)d_in[6];
    const float* g2  = (const float*)d_in[8];
    const float* bt2 = (const float*)d_in[9];
    const float* W3  = (const float*)d_in[10];
    const float* b3  = (const float*)d_in[11];

    int n = in_sizes[0] / 128;
    int e = in_sizes[1] / 2;
    const int* src = ei;
    const int* dst = ei + e;

    char* p = (char*)d_ws;
    auto alloc = [&](size_t bytes) -> char* {
        char* q = p;
        p += (bytes + 255) & ~(size_t)255;
        return q;
    };
    int*   counts  = (int*)alloc((size_t)n * 4);
    int*   offs    = (int*)alloc((size_t)(n + 1) * 4);
    int*   fill    = (int*)alloc((size_t)n * 4);
    float* dinv    = (float*)alloc((size_t)n * 4);
    int*   csr_col = (int*)alloc((size_t)e * 4);
    float* csr_val = (float*)alloc((size_t)e * 4);
    float* stats   = (float*)alloc(512 * 4);
    float* bufH    = (float*)alloc((size_t)n * 128 * 4);
    float* bufA    = (float*)alloc((size_t)n * 128 * 4);
    float* buf3    = (float*)alloc((size_t)n * 40 * 4);

    hipMemsetAsync(counts, 0, (size_t)n * 4, stream);
    hipMemsetAsync(fill, 0, (size_t)n * 4, stream);
    hipMemsetAsync(stats, 0, 512 * 4, stream);

    const int tb = 256;
    count_kernel<<<(e + tb - 1) / tb, tb, 0, stream>>>(dst, counts, e);
    scan_kernel<<<1, 1024, 0, stream>>>(counts, offs, n);
    dinv_kernel<<<(n + tb - 1) / tb, tb, 0, stream>>>(counts, dinv, n);
    scatter_kernel<<<(e + tb - 1) / tb, tb, 0, stream>>>(src, dst, offs, fill, dinv,
                                                         csr_col, csr_val, e);

    int gblocks = (n + 63) / 64;
    int ablocks = (n + 3) / 4;

    // layer 1 (b1 dropped: BN cancels constant shift)
    gemm128_kernel<<<gblocks, tb, 0, stream>>>(x, W1, bufH, n);
    aggregate128_kernel<<<ablocks, tb, 0, stream>>>(bufH, offs, csr_col, csr_val, dinv, bufA, n);
    bn_stats_kernel<<<256, tb, 0, stream>>>(bufA, stats, n);
    bn_apply_relu_kernel<<<(n * 32 + tb - 1) / tb, tb, 0, stream>>>(bufA, stats, g1, bt1, bufH,
                                                                    n, 1.0f / n);
    // layer 2
    gemm128_kernel<<<gblocks, tb, 0, stream>>>(bufH, W2, bufA, n);
    aggregate128_kernel<<<ablocks, tb, 0, stream>>>(bufA, offs, csr_col, csr_val, dinv, bufH, n);
    bn_stats_kernel<<<256, tb, 0, stream>>>(bufH, stats + 256, n);
    bn_apply_relu_kernel<<<(n * 32 + tb - 1) / tb, tb, 0, stream>>>(bufH, stats + 256, g2, bt2,
                                                                    bufA, n, 1.0f / n);
    // layer 3 + log_softmax
    gemm40_kernel<<<gblocks, tb, 0, stream>>>(bufA, W3, buf3, n);
    agg40_lsm_kernel<<<ablocks, tb, 0, stream>>>(buf3, offs, csr_col, csr_val, dinv, b3,
                                                 (float*)d_out, n);
}

// Round 2
// 471.179 us; speedup vs baseline: 1.1430x; 1.1430x over previous
//
#include <hip/hip_runtime.h>
#include <hip/hip_bf16.h>

#define EPS 1e-5f
#define SCAN_BLOCKS 256

// ---------------------------------------------------------------- degree/CSR

__global__ void count_kernel(const int* __restrict__ dst, int* __restrict__ counts, int e) {
    int i = blockIdx.x * blockDim.x + threadIdx.x;
    if (i < e) atomicAdd(&counts[dst[i]], 1);
}

__global__ void dinv_kernel(const int* __restrict__ counts, float* __restrict__ dinv, int n) {
    int i = blockIdx.x * blockDim.x + threadIdx.x;
    if (i < n) dinv[i] = rsqrtf((float)(counts[i] + 1));  // +1 self loop
}

// ---- hierarchical exclusive scan: counts[n] -> offs[n+1] -------------------

// phase 1: per-block chunk sums
__global__ __launch_bounds__(256) void scan_partial_kernel(const int* __restrict__ counts,
                                                           int* __restrict__ partials, int n) {
    __shared__ int sh[256];
    int chunk = (n + gridDim.x - 1) / gridDim.x;
    int lo = blockIdx.x * chunk;
    int hi = lo + chunk; if (hi > n) hi = n;
    int s = 0;
    for (int i = lo + threadIdx.x; i < hi; i += 256) s += counts[i];
    sh[threadIdx.x] = s;
    __syncthreads();
    for (int d = 128; d; d >>= 1) {
        if (threadIdx.x < d) sh[threadIdx.x] += sh[threadIdx.x + d];
        __syncthreads();
    }
    if (threadIdx.x == 0) partials[blockIdx.x] = sh[0];
}

// phase 2: exclusive scan of the 256 partials (single block)
__global__ __launch_bounds__(256) void scan_level2_kernel(int* __restrict__ partials) {
    __shared__ int sh[256];
    int t = threadIdx.x;
    sh[t] = partials[t];
    __syncthreads();
    for (int d = 1; d < 256; d <<= 1) {
        int v = (t >= d) ? sh[t - d] : 0;
        __syncthreads();
        sh[t] += v;
        __syncthreads();
    }
    partials[t] = (t == 0) ? 0 : sh[t - 1];
}

// phase 3: per-block re-scan + write offsets
__global__ __launch_bounds__(256) void scan_write_kernel(const int* __restrict__ counts,
                                                         const int* __restrict__ partials,
                                                         int* __restrict__ offs, int n) {
    __shared__ int sh[256];
    int t = threadIdx.x;
    int chunk = (n + gridDim.x - 1) / gridDim.x;
    int lo = blockIdx.x * chunk;
    int hi = lo + chunk; if (hi > n) hi = n;
    int per = (chunk + 255) / 256;
    int tlo = lo + t * per;
    int thi = tlo + per; if (thi > hi) thi = hi;
    int s = 0;
    for (int i = tlo; i < thi; ++i) s += counts[i];
    sh[t] = s;
    __syncthreads();
    for (int d = 1; d < 256; d <<= 1) {
        int v = (t >= d) ? sh[t - d] : 0;
        __syncthreads();
        sh[t] += v;
        __syncthreads();
    }
    int run = partials[blockIdx.x] + ((t == 0) ? 0 : sh[t - 1]);
    for (int i = tlo; i < thi; ++i) { offs[i] = run; run += counts[i]; }
}

__global__ void set_total_kernel(int* __restrict__ offs, int n, int e) {
    offs[n] = e;
}

__global__ void scatter_kernel(const int* __restrict__ src, const int* __restrict__ dst,
                               const int* __restrict__ offs, int* __restrict__ fill,
                               const float* __restrict__ dinv,
                               int* __restrict__ csr_col, float* __restrict__ csr_val, int e) {
    int i = blockIdx.x * blockDim.x + threadIdx.x;
    if (i >= e) return;
    int s = src[i], d = dst[i];
    int pos = offs[d] + atomicAdd(&fill[d], 1);
    csr_col[pos] = s;
    csr_val[pos] = dinv[s] * dinv[d];
}

// ---------------------------------------------------------------- GEMMs (fp32)

// C[n,128] = A[n,128] @ W[128,128]; W fully in LDS; 64 rows/block, 8x4 per thread
__global__ __launch_bounds__(256) void gemm128_kernel(const float* __restrict__ A,
                                                      const float* __restrict__ W,
                                                      float* __restrict__ C, int n) {
    __shared__ float Wl[128 * 128];
    int tid = threadIdx.x;
    const float4* Wv = (const float4*)W;
    float4* Wlv = (float4*)Wl;
#pragma unroll
    for (int i = 0; i < 16; ++i) Wlv[tid + 256 * i] = Wv[tid + 256 * i];
    __syncthreads();

    int ty = tid >> 5, tx = tid & 31;
    int row0 = blockIdx.x * 64 + ty * 8;
    int cb = tx * 4;
    const float* Ap[8];
#pragma unroll
    for (int r = 0; r < 8; ++r) {
        int rr = row0 + r; if (rr > n - 1) rr = n - 1;
        Ap[r] = A + (size_t)rr * 128;
    }
    float acc[8][4] = {};
    for (int k = 0; k < 128; k += 4) {
        float wk[4][4];
#pragma unroll
        for (int i = 0; i < 4; ++i)
            *(float4*)wk[i] = *(const float4*)&Wl[(k + i) * 128 + cb];
#pragma unroll
        for (int r = 0; r < 8; ++r) {
            float av[4];
            *(float4*)av = *(const float4*)(Ap[r] + k);
#pragma unroll
            for (int i = 0; i < 4; ++i)
#pragma unroll
                for (int j = 0; j < 4; ++j)
                    acc[r][j] = fmaf(av[i], wk[i][j], acc[r][j]);
        }
    }
#pragma unroll
    for (int r = 0; r < 8; ++r) {
        int rr = row0 + r;
        if (rr < n)
            *(float4*)&C[(size_t)rr * 128 + cb] =
                make_float4(acc[r][0], acc[r][1], acc[r][2], acc[r][3]);
    }
}

// C[n,40] = A[n,128] @ W[128,40]; W zero-padded to 64 cols in LDS; 64 rows/block
__global__ __launch_bounds__(256) void gemm40_kernel(const float* __restrict__ A,
                                                     const float* __restrict__ W,
                                                     float* __restrict__ C, int n) {
    __shared__ float Wl[128 * 64];
    int tid = threadIdx.x;
    for (int idx = tid; idx < 128 * 64; idx += 256) {
        int r = idx >> 6, c = idx & 63;
        Wl[idx] = (c < 40) ? W[r * 40 + c] : 0.0f;
    }
    __syncthreads();

    int ty = tid >> 4, tx = tid & 15;       // 16x16 threads
    int row0 = blockIdx.x * 64 + ty * 4;
    int cb = tx * 4;
    const float* Ap[4];
#pragma unroll
    for (int r = 0; r < 4; ++r) {
        int rr = row0 + r; if (rr > n - 1) rr = n - 1;
        Ap[r] = A + (size_t)rr * 128;
    }
    float acc[4][4] = {};
    for (int k = 0; k < 128; k += 4) {
        float wk[4][4];
#pragma unroll
        for (int i = 0; i < 4; ++i)
            *(float4*)wk[i] = *(const float4*)&Wl[(k + i) * 64 + cb];
#pragma unroll
        for (int r = 0; r < 4; ++r) {
            float av[4];
            *(float4*)av = *(const float4*)(Ap[r] + k);
#pragma unroll
            for (int i = 0; i < 4; ++i)
#pragma unroll
                for (int j = 0; j < 4; ++j)
                    acc[r][j] = fmaf(av[i], wk[i][j], acc[r][j]);
        }
    }
    if (cb < 40) {
#pragma unroll
        for (int r = 0; r < 4; ++r) {
            int rr = row0 + r;
            if (rr < n)
                *(float4*)&C[(size_t)rr * 40 + cb] =
                    make_float4(acc[r][0], acc[r][1], acc[r][2], acc[r][3]);
        }
    }
}

// ---------------------------------------------------------------- aggregation

// out[node,:] = dinv[node]^2 * H[node,:] + sum_e vals[e]*H[cols[e],:]
// one 64-lane wave per node, float2 per lane (128 features)
__global__ __launch_bounds__(256) void aggregate128_kernel(
    const float* __restrict__ H, const int* __restrict__ offs,
    const int* __restrict__ cols, const float* __restrict__ vals,
    const float* __restrict__ dinv, float* __restrict__ out, int n) {
    int node = (blockIdx.x * blockDim.x + threadIdx.x) >> 6;
    if (node >= n) return;
    int lane = threadIdx.x & 63;
    float di = dinv[node];
    float2 h0 = *(const float2*)(H + (size_t)node * 128 + lane * 2);
    float2 acc;
    acc.x = h0.x * di * di;
    acc.y = h0.y * di * di;
    int e0 = offs[node], e1 = offs[node + 1];
    for (int e = e0; e < e1; ++e) {
        int s = cols[e];
        float w = vals[e];
        float2 hv = *(const float2*)(H + (size_t)s * 128 + lane * 2);
        acc.x += hv.x * w;
        acc.y += hv.y * w;
    }
    *(float2*)(out + (size_t)node * 128 + lane * 2) = acc;
}

// final layer: aggregate 40-wide + bias + log_softmax, one wave per node
__global__ __launch_bounds__(256) void agg40_lsm_kernel(
    const float* __restrict__ H, const int* __restrict__ offs,
    const int* __restrict__ cols, const float* __restrict__ vals,
    const float* __restrict__ dinv, const float* __restrict__ b3,
    float* __restrict__ out, int n) {
    int node = (blockIdx.x * blockDim.x + threadIdx.x) >> 6;
    if (node >= n) return;
    int lane = threadIdx.x & 63;
    bool active = lane < 40;
    float di = dinv[node];
    float acc = 0.0f;
    if (active) acc = H[(size_t)node * 40 + lane] * di * di;
    int e0 = offs[node], e1 = offs[node + 1];
    for (int e = e0; e < e1; ++e) {
        int s = cols[e];
        float w = vals[e];
        if (active) acc += H[(size_t)s * 40 + lane] * w;
    }
    float v = active ? acc + b3[lane] : -1e30f;
    float m = v;
#pragma unroll
    for (int off = 32; off; off >>= 1) m = fmaxf(m, __shfl_xor(m, off));
    float ex = active ? expf(v - m) : 0.0f;
    float s = ex;
#pragma unroll
    for (int off = 32; off; off >>= 1) s += __shfl_xor(s, off);
    if (active) out[(size_t)node * 40 + lane] = v - m - logf(s);
}

// ---------------------------------------------------------------- batchnorm

// stats[c] = sum, stats[128+c] = sumsq  (atomic accumulation; pre-zeroed)
__global__ __launch_bounds__(256) void bn_stats_kernel(const float* __restrict__ X,
                                                       float* __restrict__ stats, int n) {
    int tid = threadIdx.x;
    int c = tid & 127;
    int r0 = blockIdx.x * 2 + (tid >> 7);
    float s = 0.0f, q = 0.0f;
    for (int r = r0; r < n; r += gridDim.x * 2) {
        float v = X[(size_t)r * 128 + c];
        s += v;
        q += v * v;
    }
    __shared__ float sh[256], shq[256];
    sh[tid] = s; shq[tid] = q;
    __syncthreads();
    if (tid < 128) {
        atomicAdd(&stats[c], sh[tid] + sh[tid + 128]);
        atomicAdd(&stats[128 + c], shq[tid] + shq[tid + 128]);
    }
}

__global__ void bn_apply_relu_kernel(const float* __restrict__ X,
                                     const float* __restrict__ stats,
                                     const float* __restrict__ gamma,
                                     const float* __restrict__ beta,
                                     float* __restrict__ Y, int n, float invn) {
    int i = blockIdx.x * blockDim.x + threadIdx.x;
    int total = n * 32;  // float4s
    if (i >= total) return;
    int c0 = (i & 31) * 4;
    float4 x = ((const float4*)X)[i];
    float xv[4] = {x.x, x.y, x.z, x.w};
    float o[4];
#pragma unroll
    for (int j = 0; j < 4; ++j) {
        int c = c0 + j;
        float mu = stats[c] * invn;
        float var = stats[128 + c] * invn - mu * mu;
        float sc = gamma[c] * rsqrtf(var + EPS);
        float sh = beta[c] - mu * sc;
        float v = fmaf(xv[j], sc, sh);
        o[j] = v > 0.0f ? v : 0.0f;
    }
    ((float4*)Y)[i] = make_float4(o[0], o[1], o[2], o[3]);
}

// ---------------------------------------------------------------- launch

extern "C" void kernel_launch(void* const* d_in, const int* in_sizes, int n_in,
                              void* d_out, int out_size, void* d_ws, size_t ws_size,
                              hipStream_t stream) {
    const float* x   = (const float*)d_in[0];
    const int*   ei  = (const int*)d_in[1];
    const float* W1  = (const float*)d_in[2];
    const float* g1  = (const float*)d_in[4];
    const float* bt1 = (const float*)d_in[5];
    const float* W2  = (const float*)d_in[6];
    const float* g2  = (const float*)d_in[8];
    const float* bt2 = (const float*)d_in[9];
    const float* W3  = (const float*)d_in[10];
    const float* b3  = (const float*)d_in[11];

    int n = in_sizes[0] / 128;
    int e = in_sizes[1] / 2;
    const int* src = ei;
    const int* dst = ei + e;

    char* p = (char*)d_ws;
    auto alloc = [&](size_t bytes) -> char* {
        char* q = p;
        p += (bytes + 255) & ~(size_t)255;
        return q;
    };
    int*   counts   = (int*)alloc((size_t)n * 4);
    int*   offs     = (int*)alloc((size_t)(n + 1) * 4);
    int*   fill     = (int*)alloc((size_t)n * 4);
    float* dinv     = (float*)alloc((size_t)n * 4);
    int*   partials = (int*)alloc(SCAN_BLOCKS * 4);
    int*   csr_col  = (int*)alloc((size_t)e * 4);
    float* csr_val  = (float*)alloc((size_t)e * 4);
    float* stats    = (float*)alloc(512 * 4);
    float* bufH     = (float*)alloc((size_t)n * 128 * 4);
    float* bufA     = (float*)alloc((size_t)n * 128 * 4);
    float* buf3     = (float*)alloc((size_t)n * 40 * 4);

    hipMemsetAsync(counts, 0, (size_t)n * 4, stream);
    hipMemsetAsync(fill, 0, (size_t)n * 4, stream);
    hipMemsetAsync(stats, 0, 512 * 4, stream);

    const int tb = 256;
    count_kernel<<<(e + tb - 1) / tb, tb, 0, stream>>>(dst, counts, e);
    scan_partial_kernel<<<SCAN_BLOCKS, tb, 0, stream>>>(counts, partials, n);
    scan_level2_kernel<<<1, tb, 0, stream>>>(partials);
    scan_write_kernel<<<SCAN_BLOCKS, tb, 0, stream>>>(counts, partials, offs, n);
    set_total_kernel<<<1, 1, 0, stream>>>(offs, n, e);
    dinv_kernel<<<(n + tb - 1) / tb, tb, 0, stream>>>(counts, dinv, n);
    scatter_kernel<<<(e + tb - 1) / tb, tb, 0, stream>>>(src, dst, offs, fill, dinv,
                                                         csr_col, csr_val, e);

    int gblocks = (n + 63) / 64;
    int ablocks = (n + 3) / 4;

    // layer 1 (b1 dropped: BN cancels constant shift)
    gemm128_kernel<<<gblocks, tb, 0, stream>>>(x, W1, bufH, n);
    aggregate128_kernel<<<ablocks, tb, 0, stream>>>(bufH, offs, csr_col, csr_val, dinv, bufA, n);
    bn_stats_kernel<<<256, tb, 0, stream>>>(bufA, stats, n);
    bn_apply_relu_kernel<<<(n * 32 + tb - 1) / tb, tb, 0, stream>>>(bufA, stats, g1, bt1, bufH,
                                                                    n, 1.0f / n);
    // layer 2
    gemm128_kernel<<<gblocks, tb, 0, stream>>>(bufH, W2, bufA, n);
    aggregate128_kernel<<<ablocks, tb, 0, stream>>>(bufA, offs, csr_col, csr_val, dinv, bufH, n);
    bn_stats_kernel<<<256, tb, 0, stream>>>(bufH, stats + 256, n);
    bn_apply_relu_kernel<<<(n * 32 + tb - 1) / tb, tb, 0, stream>>>(bufH, stats + 256, g2, bt2,
                                                                    bufA, n, 1.0f / n);
    // layer 3 + log_softmax
    gemm40_kernel<<<gblocks, tb, 0, stream>>>(bufA, W3, buf3, n);
    agg40_lsm_kernel<<<ablocks, tb, 0, stream>>>(buf3, offs, csr_col, csr_val, dinv, b3,
                                                 (float*)d_out, n);
}

// Round 3
// 450.391 us; speedup vs baseline: 1.1957x; 1.0462x over previous
//
#include <hip/hip_runtime.h>
#include <hip/hip_bf16.h>

#define EPS 1e-5f
#define SCAN_BLOCKS 256

__device__ inline float bf2f(unsigned short u) {
    union { unsigned int i; float f; } v;
    v.i = ((unsigned int)u) << 16;
    return v.f;
}

__device__ inline unsigned short f2bf(float f) {
    union { float f; unsigned int i; } v;
    v.f = f;
    unsigned int x = v.i;
    unsigned int rounded = x + 0x7FFF + ((x >> 16) & 1);   // RNE
    return (unsigned short)(rounded >> 16);
}

// ---------------------------------------------------------------- degree/CSR

__global__ void count_kernel(const int* __restrict__ dst, int* __restrict__ counts, int e) {
    int i = blockIdx.x * blockDim.x + threadIdx.x;
    if (i < e) atomicAdd(&counts[dst[i]], 1);
}

__global__ void dinv_kernel(const int* __restrict__ counts, float* __restrict__ dinv, int n) {
    int i = blockIdx.x * blockDim.x + threadIdx.x;
    if (i < n) dinv[i] = rsqrtf((float)(counts[i] + 1));  // +1 self loop
}

// ---- hierarchical exclusive scan: counts[n] -> offs[n+1] -------------------

__global__ __launch_bounds__(256) void scan_partial_kernel(const int* __restrict__ counts,
                                                           int* __restrict__ partials, int n) {
    __shared__ int sh[256];
    int chunk = (n + gridDim.x - 1) / gridDim.x;
    int lo = blockIdx.x * chunk;
    int hi = lo + chunk; if (hi > n) hi = n;
    int s = 0;
    for (int i = lo + threadIdx.x; i < hi; i += 256) s += counts[i];
    sh[threadIdx.x] = s;
    __syncthreads();
    for (int d = 128; d; d >>= 1) {
        if (threadIdx.x < d) sh[threadIdx.x] += sh[threadIdx.x + d];
        __syncthreads();
    }
    if (threadIdx.x == 0) partials[blockIdx.x] = sh[0];
}

__global__ __launch_bounds__(256) void scan_level2_kernel(int* __restrict__ partials) {
    __shared__ int sh[256];
    int t = threadIdx.x;
    sh[t] = partials[t];
    __syncthreads();
    for (int d = 1; d < 256; d <<= 1) {
        int v = (t >= d) ? sh[t - d] : 0;
        __syncthreads();
        sh[t] += v;
        __syncthreads();
    }
    partials[t] = (t == 0) ? 0 : sh[t - 1];
}

__global__ __launch_bounds__(256) void scan_write_kernel(const int* __restrict__ counts,
                                                         const int* __restrict__ partials,
                                                         int* __restrict__ offs, int n) {
    __shared__ int sh[256];
    int t = threadIdx.x;
    int chunk = (n + gridDim.x - 1) / gridDim.x;
    int lo = blockIdx.x * chunk;
    int hi = lo + chunk; if (hi > n) hi = n;
    int per = (chunk + 255) / 256;
    int tlo = lo + t * per;
    int thi = tlo + per; if (thi > hi) thi = hi;
    int s = 0;
    for (int i = tlo; i < thi; ++i) s += counts[i];
    sh[t] = s;
    __syncthreads();
    for (int d = 1; d < 256; d <<= 1) {
        int v = (t >= d) ? sh[t - d] : 0;
        __syncthreads();
        sh[t] += v;
        __syncthreads();
    }
    int run = partials[blockIdx.x] + ((t == 0) ? 0 : sh[t - 1]);
    for (int i = tlo; i < thi; ++i) { offs[i] = run; run += counts[i]; }
}

__global__ void set_total_kernel(int* __restrict__ offs, int n, int e) {
    offs[n] = e;
}

__global__ void scatter_kernel(const int* __restrict__ src, const int* __restrict__ dst,
                               const int* __restrict__ offs, int* __restrict__ fill,
                               const float* __restrict__ dinv,
                               int* __restrict__ csr_col, float* __restrict__ csr_val, int e) {
    int i = blockIdx.x * blockDim.x + threadIdx.x;
    if (i >= e) return;
    int s = src[i], d = dst[i];
    int pos = offs[d] + atomicAdd(&fill[d], 1);
    csr_col[pos] = s;
    csr_val[pos] = dinv[s] * dinv[d];
}

// ---------------------------------------------------------------- GEMMs (fp32 in, bf16 out)

// C[n,128](bf16) = A[n,128](f32) @ W[128,128](f32); W in LDS; 64 rows/block
__global__ __launch_bounds__(256) void gemm128_kernel(const float* __restrict__ A,
                                                      const float* __restrict__ W,
                                                      unsigned short* __restrict__ C, int n) {
    __shared__ float Wl[128 * 128];
    int tid = threadIdx.x;
    const float4* Wv = (const float4*)W;
    float4* Wlv = (float4*)Wl;
#pragma unroll
    for (int i = 0; i < 16; ++i) Wlv[tid + 256 * i] = Wv[tid + 256 * i];
    __syncthreads();

    int ty = tid >> 5, tx = tid & 31;
    int row0 = blockIdx.x * 64 + ty * 8;
    int cb = tx * 4;
    const float* Ap[8];
#pragma unroll
    for (int r = 0; r < 8; ++r) {
        int rr = row0 + r; if (rr > n - 1) rr = n - 1;
        Ap[r] = A + (size_t)rr * 128;
    }
    float acc[8][4] = {};
    for (int k = 0; k < 128; k += 4) {
        float wk[4][4];
#pragma unroll
        for (int i = 0; i < 4; ++i)
            *(float4*)wk[i] = *(const float4*)&Wl[(k + i) * 128 + cb];
#pragma unroll
        for (int r = 0; r < 8; ++r) {
            float av[4];
            *(float4*)av = *(const float4*)(Ap[r] + k);
#pragma unroll
            for (int i = 0; i < 4; ++i)
#pragma unroll
                for (int j = 0; j < 4; ++j)
                    acc[r][j] = fmaf(av[i], wk[i][j], acc[r][j]);
        }
    }
#pragma unroll
    for (int r = 0; r < 8; ++r) {
        int rr = row0 + r;
        if (rr < n) {
            ushort4 o;
            o.x = f2bf(acc[r][0]); o.y = f2bf(acc[r][1]);
            o.z = f2bf(acc[r][2]); o.w = f2bf(acc[r][3]);
            *(ushort4*)&C[(size_t)rr * 128 + cb] = o;
        }
    }
}

// C[n,40](bf16) = A[n,128](f32) @ W[128,40](f32)
__global__ __launch_bounds__(256) void gemm40_kernel(const float* __restrict__ A,
                                                     const float* __restrict__ W,
                                                     unsigned short* __restrict__ C, int n) {
    __shared__ float Wl[128 * 64];
    int tid = threadIdx.x;
    for (int idx = tid; idx < 128 * 64; idx += 256) {
        int r = idx >> 6, c = idx & 63;
        Wl[idx] = (c < 40) ? W[r * 40 + c] : 0.0f;
    }
    __syncthreads();

    int ty = tid >> 4, tx = tid & 15;       // 16x16 threads
    int row0 = blockIdx.x * 64 + ty * 4;
    int cb = tx * 4;
    const float* Ap[4];
#pragma unroll
    for (int r = 0; r < 4; ++r) {
        int rr = row0 + r; if (rr > n - 1) rr = n - 1;
        Ap[r] = A + (size_t)rr * 128;
    }
    float acc[4][4] = {};
    for (int k = 0; k < 128; k += 4) {
        float wk[4][4];
#pragma unroll
        for (int i = 0; i < 4; ++i)
            *(float4*)wk[i] = *(const float4*)&Wl[(k + i) * 64 + cb];
#pragma unroll
        for (int r = 0; r < 4; ++r) {
            float av[4];
            *(float4*)av = *(const float4*)(Ap[r] + k);
#pragma unroll
            for (int i = 0; i < 4; ++i)
#pragma unroll
                for (int j = 0; j < 4; ++j)
                    acc[r][j] = fmaf(av[i], wk[i][j], acc[r][j]);
        }
    }
    if (cb < 40) {
#pragma unroll
        for (int r = 0; r < 4; ++r) {
            int rr = row0 + r;
            if (rr < n) {
                ushort4 o;
                o.x = f2bf(acc[r][0]); o.y = f2bf(acc[r][1]);
                o.z = f2bf(acc[r][2]); o.w = f2bf(acc[r][3]);
                *(ushort4*)&C[(size_t)rr * 40 + cb] = o;
            }
        }
    }
}

// ---------------------------------------------------------------- aggregation

// out[node,:](f32) = dinv^2 * H[node,:] + sum_e vals[e]*H[cols[e],:], H in bf16
// one 64-lane wave per node; lane holds 2 features (one dword of 2 bf16)
__global__ __launch_bounds__(256) void aggregate128_kernel(
    const unsigned short* __restrict__ H, const int* __restrict__ offs,
    const int* __restrict__ cols, const float* __restrict__ vals,
    const float* __restrict__ dinv, float* __restrict__ out, int n) {
    int node = (blockIdx.x * blockDim.x + threadIdx.x) >> 6;
    if (node >= n) return;
    int lane = threadIdx.x & 63;
    float di = dinv[node];
    unsigned int h0 = *(const unsigned int*)(H + (size_t)node * 128 + lane * 2);
    float2 acc;
    acc.x = bf2f((unsigned short)h0) * di * di;
    acc.y = bf2f((unsigned short)(h0 >> 16)) * di * di;
    int e0 = offs[node], e1 = offs[node + 1];
    for (int e = e0; e < e1; ++e) {
        int s = cols[e];
        float w = vals[e];
        unsigned int hv = *(const unsigned int*)(H + (size_t)s * 128 + lane * 2);
        acc.x += bf2f((unsigned short)hv) * w;
        acc.y += bf2f((unsigned short)(hv >> 16)) * w;
    }
    *(float2*)(out + (size_t)node * 128 + lane * 2) = acc;
}

// final layer: aggregate 40-wide bf16 + bias + log_softmax, one wave per node
__global__ __launch_bounds__(256) void agg40_lsm_kernel(
    const unsigned short* __restrict__ H, const int* __restrict__ offs,
    const int* __restrict__ cols, const float* __restrict__ vals,
    const float* __restrict__ dinv, const float* __restrict__ b3,
    float* __restrict__ out, int n) {
    int node = (blockIdx.x * blockDim.x + threadIdx.x) >> 6;
    if (node >= n) return;
    int lane = threadIdx.x & 63;
    bool active = lane < 40;
    float di = dinv[node];
    float acc = 0.0f;
    if (active) acc = bf2f(H[(size_t)node * 40 + lane]) * di * di;
    int e0 = offs[node], e1 = offs[node + 1];
    for (int e = e0; e < e1; ++e) {
        int s = cols[e];
        float w = vals[e];
        if (active) acc += bf2f(H[(size_t)s * 40 + lane]) * w;
    }
    float v = active ? acc + b3[lane] : -1e30f;
    float m = v;
#pragma unroll
    for (int off = 32; off; off >>= 1) m = fmaxf(m, __shfl_xor(m, off));
    float ex = active ? expf(v - m) : 0.0f;
    float s = ex;
#pragma unroll
    for (int off = 32; off; off >>= 1) s += __shfl_xor(s, off);
    if (active) out[(size_t)node * 40 + lane] = v - m - logf(s);
}

// ---------------------------------------------------------------- batchnorm

__global__ __launch_bounds__(256) void bn_stats_kernel(const float* __restrict__ X,
                                                       float* __restrict__ stats, int n) {
    int tid = threadIdx.x;
    int c = tid & 127;
    int r0 = blockIdx.x * 2 + (tid >> 7);
    float s = 0.0f, q = 0.0f;
    for (int r = r0; r < n; r += gridDim.x * 2) {
        float v = X[(size_t)r * 128 + c];
        s += v;
        q += v * v;
    }
    __shared__ float sh[256], shq[256];
    sh[tid] = s; shq[tid] = q;
    __syncthreads();
    if (tid < 128) {
        atomicAdd(&stats[c], sh[tid] + sh[tid + 128]);
        atomicAdd(&stats[128 + c], shq[tid] + shq[tid + 128]);
    }
}

__global__ void bn_apply_relu_kernel(const float* __restrict__ X,
                                     const float* __restrict__ stats,
                                     const float* __restrict__ gamma,
                                     const float* __restrict__ beta,
                                     float* __restrict__ Y, int n, float invn) {
    int i = blockIdx.x * blockDim.x + threadIdx.x;
    int total = n * 32;  // float4s
    if (i >= total) return;
    int c0 = (i & 31) * 4;
    float4 x = ((const float4*)X)[i];
    float xv[4] = {x.x, x.y, x.z, x.w};
    float o[4];
#pragma unroll
    for (int j = 0; j < 4; ++j) {
        int c = c0 + j;
        float mu = stats[c] * invn;
        float var = stats[128 + c] * invn - mu * mu;
        float sc = gamma[c] * rsqrtf(var + EPS);
        float sh = beta[c] - mu * sc;
        float v = fmaf(xv[j], sc, sh);
        o[j] = v > 0.0f ? v : 0.0f;
    }
    ((float4*)Y)[i] = make_float4(o[0], o[1], o[2], o[3]);
}

// ---------------------------------------------------------------- launch

extern "C" void kernel_launch(void* const* d_in, const int* in_sizes, int n_in,
                              void* d_out, int out_size, void* d_ws, size_t ws_size,
                              hipStream_t stream) {
    const float* x   = (const float*)d_in[0];
    const int*   ei  = (const int*)d_in[1];
    const float* W1  = (const float*)d_in[2];
    const float* g1  = (const float*)d_in[4];
    const float* bt1 = (const float*)d_in[5];
    const float* W2  = (const float*)d_in[6];
    const float* g2  = (const float*)d_in[8];
    const float* bt2 = (const float*)d_in[9];
    const float* W3  = (const float*)d_in[10];
    const float* b3  = (const float*)d_in[11];

    int n = in_sizes[0] / 128;
    int e = in_sizes[1] / 2;
    const int* src = ei;
    const int* dst = ei + e;

    char* p = (char*)d_ws;
    auto alloc = [&](size_t bytes) -> char* {
        char* q = p;
        p += (bytes + 255) & ~(size_t)255;
        return q;
    };
    int*            counts   = (int*)alloc((size_t)n * 4);
    int*            offs     = (int*)alloc((size_t)(n + 1) * 4);
    int*            fill     = (int*)alloc((size_t)n * 4);
    float*          dinv     = (float*)alloc((size_t)n * 4);
    int*            partials = (int*)alloc(SCAN_BLOCKS * 4);
    int*            csr_col  = (int*)alloc((size_t)e * 4);
    float*          csr_val  = (float*)alloc((size_t)e * 4);
    float*          stats    = (float*)alloc(512 * 4);
    unsigned short* bufHb    = (unsigned short*)alloc((size_t)n * 128 * 2);  // bf16 gather operand
    float*          bufA     = (float*)alloc((size_t)n * 128 * 4);           // aggregated f32
    float*          bufH     = (float*)alloc((size_t)n * 128 * 4);           // BN output (gemm in)
    unsigned short* buf3b    = (unsigned short*)alloc((size_t)n * 40 * 2);   // layer-3 bf16

    hipMemsetAsync(counts, 0, (size_t)n * 4, stream);
    hipMemsetAsync(fill, 0, (size_t)n * 4, stream);
    hipMemsetAsync(stats, 0, 512 * 4, stream);

    const int tb = 256;
    count_kernel<<<(e + tb - 1) / tb, tb, 0, stream>>>(dst, counts, e);
    scan_partial_kernel<<<SCAN_BLOCKS, tb, 0, stream>>>(counts, partials, n);
    scan_level2_kernel<<<1, tb, 0, stream>>>(partials);
    scan_write_kernel<<<SCAN_BLOCKS, tb, 0, stream>>>(counts, partials, offs, n);
    set_total_kernel<<<1, 1, 0, stream>>>(offs, n, e);
    dinv_kernel<<<(n + tb - 1) / tb, tb, 0, stream>>>(counts, dinv, n);
    scatter_kernel<<<(e + tb - 1) / tb, tb, 0, stream>>>(src, dst, offs, fill, dinv,
                                                         csr_col, csr_val, e);

    int gblocks = (n + 63) / 64;
    int ablocks = (n + 3) / 4;

    // layer 1 (b1 dropped: BN cancels constant shift)
    gemm128_kernel<<<gblocks, tb, 0, stream>>>(x, W1, bufHb, n);
    aggregate128_kernel<<<ablocks, tb, 0, stream>>>(bufHb, offs, csr_col, csr_val, dinv, bufA, n);
    bn_stats_kernel<<<256, tb, 0, stream>>>(bufA, stats, n);
    bn_apply_relu_kernel<<<(n * 32 + tb - 1) / tb, tb, 0, stream>>>(bufA, stats, g1, bt1, bufH,
                                                                    n, 1.0f / n);
    // layer 2
    gemm128_kernel<<<gblocks, tb, 0, stream>>>(bufH, W2, bufHb, n);
    aggregate128_kernel<<<ablocks, tb, 0, stream>>>(bufHb, offs, csr_col, csr_val, dinv, bufA, n);
    bn_stats_kernel<<<256, tb, 0, stream>>>(bufA, stats + 256, n);
    bn_apply_relu_kernel<<<(n * 32 + tb - 1) / tb, tb, 0, stream>>>(bufA, stats + 256, g2, bt2,
                                                                    bufH, n, 1.0f / n);
    // layer 3 + log_softmax
    gemm40_kernel<<<gblocks, tb, 0, stream>>>(bufH, W3, buf3b, n);
    agg40_lsm_kernel<<<ablocks, tb, 0, stream>>>(buf3b, offs, csr_col, csr_val, dinv, b3,
                                                 (float*)d_out, n);
}

// Round 4
// 390.885 us; speedup vs baseline: 1.3778x; 1.1522x over previous
//
#include <hip/hip_runtime.h>
#include <hip/hip_bf16.h>

#define EPS 1e-5f
#define SCAN_BLOCKS 256

__device__ inline float bf2f(unsigned short u) {
    union { unsigned int i; float f; } v;
    v.i = ((unsigned int)u) << 16;
    return v.f;
}

__device__ inline unsigned short f2bf(float f) {
    union { float f; unsigned int i; } v;
    v.f = f;
    unsigned int x = v.i;
    unsigned int rounded = x + 0x7FFF + ((x >> 16) & 1);   // RNE
    return (unsigned short)(rounded >> 16);
}

// ---------------------------------------------------------------- degree/CSR

__global__ void count_kernel(const int* __restrict__ dst, int* __restrict__ counts, int e) {
    int i = blockIdx.x * blockDim.x + threadIdx.x;
    if (i < e) atomicAdd(&counts[dst[i]], 1);
}

// ---- hierarchical exclusive scan: counts[n] -> offs[n+1] (+dinv fused) -----

__global__ __launch_bounds__(256) void scan_partial_kernel(const int* __restrict__ counts,
                                                           int* __restrict__ partials, int n) {
    __shared__ int sh[256];
    int chunk = (n + gridDim.x - 1) / gridDim.x;
    int lo = blockIdx.x * chunk;
    int hi = lo + chunk; if (hi > n) hi = n;
    int s = 0;
    for (int i = lo + threadIdx.x; i < hi; i += 256) s += counts[i];
    sh[threadIdx.x] = s;
    __syncthreads();
    for (int d = 128; d; d >>= 1) {
        if (threadIdx.x < d) sh[threadIdx.x] += sh[threadIdx.x + d];
        __syncthreads();
    }
    if (threadIdx.x == 0) partials[blockIdx.x] = sh[0];
}

__global__ __launch_bounds__(256) void scan_level2_kernel(int* __restrict__ partials) {
    __shared__ int sh[256];
    int t = threadIdx.x;
    sh[t] = partials[t];
    __syncthreads();
    for (int d = 1; d < 256; d <<= 1) {
        int v = (t >= d) ? sh[t - d] : 0;
        __syncthreads();
        sh[t] += v;
        __syncthreads();
    }
    partials[t] = (t == 0) ? 0 : sh[t - 1];
}

// also writes dinv[] and offs[n]
__global__ __launch_bounds__(256) void scan_write_kernel(const int* __restrict__ counts,
                                                         const int* __restrict__ partials,
                                                         int* __restrict__ offs,
                                                         float* __restrict__ dinv, int n) {
    __shared__ int sh[256];
    int t = threadIdx.x;
    int chunk = (n + gridDim.x - 1) / gridDim.x;
    int lo = blockIdx.x * chunk;
    int hi = lo + chunk; if (hi > n) hi = n;
    int per = (chunk + 255) / 256;
    int tlo = lo + t * per;
    int thi = tlo + per; if (thi > hi) thi = hi;
    int s = 0;
    for (int i = tlo; i < thi; ++i) s += counts[i];
    sh[t] = s;
    __syncthreads();
    for (int d = 1; d < 256; d <<= 1) {
        int v = (t >= d) ? sh[t - d] : 0;
        __syncthreads();
        sh[t] += v;
        __syncthreads();
    }
    int run = partials[blockIdx.x] + ((t == 0) ? 0 : sh[t - 1]);
    for (int i = tlo; i < thi; ++i) {
        offs[i] = run;
        run += counts[i];
        dinv[i] = rsqrtf((float)(counts[i] + 1));  // +1 self loop
    }
    if (tlo < n && thi == n) offs[n] = run;
}

__global__ void scatter_kernel(const int* __restrict__ src, const int* __restrict__ dst,
                               const int* __restrict__ offs, int* __restrict__ fill,
                               const float* __restrict__ dinv,
                               int* __restrict__ csr_col, float* __restrict__ csr_val, int e) {
    int i = blockIdx.x * blockDim.x + threadIdx.x;
    if (i >= e) return;
    int s = src[i], d = dst[i];
    int pos = offs[d] + atomicAdd(&fill[d], 1);
    csr_col[pos] = s;
    csr_val[pos] = dinv[s] * dinv[d];
}

// ---------------------------------------------------------------- GEMMs

// C[n,128](bf16) = A[n,128](f32) @ W[128,128](f32); W in LDS; 64 rows/block
__global__ __launch_bounds__(256) void gemm128_kernel(const float* __restrict__ A,
                                                      const float* __restrict__ W,
                                                      unsigned short* __restrict__ C, int n) {
    __shared__ float Wl[128 * 128];
    int tid = threadIdx.x;
    const float4* Wv = (const float4*)W;
    float4* Wlv = (float4*)Wl;
#pragma unroll
    for (int i = 0; i < 16; ++i) Wlv[tid + 256 * i] = Wv[tid + 256 * i];
    __syncthreads();

    int ty = tid >> 5, tx = tid & 31;
    int row0 = blockIdx.x * 64 + ty * 8;
    int cb = tx * 4;
    const float* Ap[8];
#pragma unroll
    for (int r = 0; r < 8; ++r) {
        int rr = row0 + r; if (rr > n - 1) rr = n - 1;
        Ap[r] = A + (size_t)rr * 128;
    }
    float acc[8][4] = {};
    for (int k = 0; k < 128; k += 4) {
        float wk[4][4];
#pragma unroll
        for (int i = 0; i < 4; ++i)
            *(float4*)wk[i] = *(const float4*)&Wl[(k + i) * 128 + cb];
#pragma unroll
        for (int r = 0; r < 8; ++r) {
            float av[4];
            *(float4*)av = *(const float4*)(Ap[r] + k);
#pragma unroll
            for (int i = 0; i < 4; ++i)
#pragma unroll
                for (int j = 0; j < 4; ++j)
                    acc[r][j] = fmaf(av[i], wk[i][j], acc[r][j]);
        }
    }
#pragma unroll
    for (int r = 0; r < 8; ++r) {
        int rr = row0 + r;
        if (rr < n) {
            ushort4 o;
            o.x = f2bf(acc[r][0]); o.y = f2bf(acc[r][1]);
            o.z = f2bf(acc[r][2]); o.w = f2bf(acc[r][3]);
            *(ushort4*)&C[(size_t)rr * 128 + cb] = o;
        }
    }
}

// out[n,40](f32) = log_softmax(A[n,128](f32) @ W[128,40] + b3), fused epilogue
__global__ __launch_bounds__(256) void gemm40_lsm_kernel(const float* __restrict__ A,
                                                         const float* __restrict__ W,
                                                         const float* __restrict__ b3,
                                                         float* __restrict__ out, int n) {
    __shared__ float Wl[128 * 64];
    __shared__ float sRow[64 * 45];   // 45 stride: conflict-light column reads
    __shared__ float sD[64];
    __shared__ float sB[40];
    int tid = threadIdx.x;
    if (tid < 40) sB[tid] = b3[tid];
    for (int idx = tid; idx < 128 * 64; idx += 256) {
        int r = idx >> 6, c = idx & 63;
        Wl[idx] = (c < 40) ? W[r * 40 + c] : 0.0f;
    }
    __syncthreads();

    int ty = tid >> 4, tx = tid & 15;       // 16x16 threads
    int row0 = blockIdx.x * 64 + ty * 4;
    int cb = tx * 4;
    const float* Ap[4];
#pragma unroll
    for (int r = 0; r < 4; ++r) {
        int rr = row0 + r; if (rr > n - 1) rr = n - 1;
        Ap[r] = A + (size_t)rr * 128;
    }
    float acc[4][4] = {};
    for (int k = 0; k < 128; k += 4) {
        float wk[4][4];
#pragma unroll
        for (int i = 0; i < 4; ++i)
            *(float4*)wk[i] = *(const float4*)&Wl[(k + i) * 64 + cb];
#pragma unroll
        for (int r = 0; r < 4; ++r) {
            float av[4];
            *(float4*)av = *(const float4*)(Ap[r] + k);
#pragma unroll
            for (int i = 0; i < 4; ++i)
#pragma unroll
                for (int j = 0; j < 4; ++j)
                    acc[r][j] = fmaf(av[i], wk[i][j], acc[r][j]);
        }
    }
    // stash logits (+bias) for row reduction
    if (cb < 40) {
#pragma unroll
        for (int r = 0; r < 4; ++r)
#pragma unroll
            for (int j = 0; j < 4; ++j)
                sRow[(ty * 4 + r) * 45 + cb + j] = acc[r][j] + sB[cb + j];
    }
    __syncthreads();
    if (tid < 64) {
        float m = -1e30f;
        for (int c = 0; c < 40; ++c) m = fmaxf(m, sRow[tid * 45 + c]);
        float l = 0.0f;
        for (int c = 0; c < 40; ++c) l += expf(sRow[tid * 45 + c] - m);
        sD[tid] = m + logf(l);
    }
    __syncthreads();
    if (cb < 40) {
#pragma unroll
        for (int r = 0; r < 4; ++r) {
            int rr = row0 + r;
            if (rr < n) {
                float d = sD[ty * 4 + r];
                float4 o;
                o.x = acc[r][0] + sB[cb + 0] - d;
                o.y = acc[r][1] + sB[cb + 1] - d;
                o.z = acc[r][2] + sB[cb + 2] - d;
                o.w = acc[r][3] + sB[cb + 3] - d;
                *(float4*)&out[(size_t)rr * 40 + cb] = o;
            }
        }
    }
}

// ---------------------------------------------------------------- aggregation

// out[node,:](f32) = dinv^2 * H[node,:] + sum_e vals[e]*H[cols[e],:], H bf16
// one 64-lane wave per node; 2-edge unroll for MLP
__global__ __launch_bounds__(256) void aggregate128_kernel(
    const unsigned short* __restrict__ H, const int* __restrict__ offs,
    const int* __restrict__ cols, const float* __restrict__ vals,
    const float* __restrict__ dinv, float* __restrict__ out, int n) {
    int node = (blockIdx.x * blockDim.x + threadIdx.x) >> 6;
    if (node >= n) return;
    int lane = threadIdx.x & 63;
    float di = dinv[node];
    unsigned int h0 = *(const unsigned int*)(H + (size_t)node * 128 + lane * 2);
    float2 acc0, acc1;
    acc0.x = bf2f((unsigned short)h0) * di * di;
    acc0.y = bf2f((unsigned short)(h0 >> 16)) * di * di;
    acc1.x = 0.0f; acc1.y = 0.0f;
    int e0 = offs[node], e1 = offs[node + 1];
    int e = e0;
    for (; e + 2 <= e1; e += 2) {
        int sA = cols[e], sB = cols[e + 1];
        float wA = vals[e], wB = vals[e + 1];
        unsigned int hA = *(const unsigned int*)(H + (size_t)sA * 128 + lane * 2);
        unsigned int hB = *(const unsigned int*)(H + (size_t)sB * 128 + lane * 2);
        acc0.x += bf2f((unsigned short)hA) * wA;
        acc0.y += bf2f((unsigned short)(hA >> 16)) * wA;
        acc1.x += bf2f((unsigned short)hB) * wB;
        acc1.y += bf2f((unsigned short)(hB >> 16)) * wB;
    }
    if (e < e1) {
        int sA = cols[e];
        float wA = vals[e];
        unsigned int hA = *(const unsigned int*)(H + (size_t)sA * 128 + lane * 2);
        acc0.x += bf2f((unsigned short)hA) * wA;
        acc0.y += bf2f((unsigned short)(hA >> 16)) * wA;
    }
    acc0.x += acc1.x;
    acc0.y += acc1.y;
    *(float2*)(out + (size_t)node * 128 + lane * 2) = acc0;
}

// ---------------------------------------------------------------- batchnorm

__global__ __launch_bounds__(256) void bn_stats_kernel(const float* __restrict__ X,
                                                       float* __restrict__ stats, int n) {
    int tid = threadIdx.x;
    int c = tid & 127;
    int r0 = blockIdx.x * 2 + (tid >> 7);
    float s = 0.0f, q = 0.0f;
    for (int r = r0; r < n; r += gridDim.x * 2) {
        float v = X[(size_t)r * 128 + c];
        s += v;
        q += v * v;
    }
    __shared__ float sh[256], shq[256];
    sh[tid] = s; shq[tid] = q;
    __syncthreads();
    if (tid < 128) {
        atomicAdd(&stats[c], sh[tid] + sh[tid + 128]);
        atomicAdd(&stats[128 + c], shq[tid] + shq[tid + 128]);
    }
}

// f32 output (feeds next gemm128)
__global__ void bn_apply_relu_kernel(const float* __restrict__ X,
                                     const float* __restrict__ stats,
                                     const float* __restrict__ gamma,
                                     const float* __restrict__ beta,
                                     float* __restrict__ Y, int n, float invn) {
    int i = blockIdx.x * blockDim.x + threadIdx.x;
    int total = n * 32;  // float4s
    if (i >= total) return;
    int c0 = (i & 31) * 4;
    float4 x = ((const float4*)X)[i];
    float xv[4] = {x.x, x.y, x.z, x.w};
    float o[4];
#pragma unroll
    for (int j = 0; j < 4; ++j) {
        int c = c0 + j;
        float mu = stats[c] * invn;
        float var = stats[128 + c] * invn - mu * mu;
        float sc = gamma[c] * rsqrtf(var + EPS);
        float sh = beta[c] - mu * sc;
        float v = fmaf(xv[j], sc, sh);
        o[j] = v > 0.0f ? v : 0.0f;
    }
    ((float4*)Y)[i] = make_float4(o[0], o[1], o[2], o[3]);
}

// bf16-only output (feeds final aggregation)
__global__ void bn_apply_relu_bf16_kernel(const float* __restrict__ X,
                                          const float* __restrict__ stats,
                                          const float* __restrict__ gamma,
                                          const float* __restrict__ beta,
                                          unsigned short* __restrict__ Y, int n, float invn) {
    int i = blockIdx.x * blockDim.x + threadIdx.x;
    int total = n * 32;  // float4s
    if (i >= total) return;
    int c0 = (i & 31) * 4;
    float4 x = ((const float4*)X)[i];
    float xv[4] = {x.x, x.y, x.z, x.w};
    ushort4 o;
    unsigned short ov[4];
#pragma unroll
    for (int j = 0; j < 4; ++j) {
        int c = c0 + j;
        float mu = stats[c] * invn;
        float var = stats[128 + c] * invn - mu * mu;
        float sc = gamma[c] * rsqrtf(var + EPS);
        float sh = beta[c] - mu * sc;
        float v = fmaf(xv[j], sc, sh);
        ov[j] = f2bf(v > 0.0f ? v : 0.0f);
    }
    o.x = ov[0]; o.y = ov[1]; o.z = ov[2]; o.w = ov[3];
    ((ushort4*)Y)[i] = o;
}

// ---------------------------------------------------------------- launch

extern "C" void kernel_launch(void* const* d_in, const int* in_sizes, int n_in,
                              void* d_out, int out_size, void* d_ws, size_t ws_size,
                              hipStream_t stream) {
    const float* x   = (const float*)d_in[0];
    const int*   ei  = (const int*)d_in[1];
    const float* W1  = (const float*)d_in[2];
    const float* g1  = (const float*)d_in[4];
    const float* bt1 = (const float*)d_in[5];
    const float* W2  = (const float*)d_in[6];
    const float* g2  = (const float*)d_in[8];
    const float* bt2 = (const float*)d_in[9];
    const float* W3  = (const float*)d_in[10];
    const float* b3  = (const float*)d_in[11];

    int n = in_sizes[0] / 128;
    int e = in_sizes[1] / 2;
    const int* src = ei;
    const int* dst = ei + e;

    char* p = (char*)d_ws;
    auto alloc = [&](size_t bytes) -> char* {
        char* q = p;
        p += (bytes + 255) & ~(size_t)255;
        return q;
    };
    int*            counts   = (int*)alloc((size_t)n * 4);
    int*            offs     = (int*)alloc((size_t)(n + 1) * 4);
    int*            fill     = (int*)alloc((size_t)n * 4);
    float*          dinv     = (float*)alloc((size_t)n * 4);
    int*            partials = (int*)alloc(SCAN_BLOCKS * 4);
    int*            csr_col  = (int*)alloc((size_t)e * 4);
    float*          csr_val  = (float*)alloc((size_t)e * 4);
    float*          stats    = (float*)alloc(512 * 4);
    unsigned short* Hb       = (unsigned short*)alloc((size_t)n * 128 * 2);  // bf16 gather operand
    float*          bufA     = (float*)alloc((size_t)n * 128 * 4);
    float*          bufB     = (float*)alloc((size_t)n * 128 * 4);

    hipMemsetAsync(counts, 0, (size_t)n * 4, stream);
    hipMemsetAsync(fill, 0, (size_t)n * 4, stream);
    hipMemsetAsync(stats, 0, 512 * 4, stream);

    const int tb = 256;
    count_kernel<<<(e + tb - 1) / tb, tb, 0, stream>>>(dst, counts, e);
    scan_partial_kernel<<<SCAN_BLOCKS, tb, 0, stream>>>(counts, partials, n);
    scan_level2_kernel<<<1, tb, 0, stream>>>(partials);
    scan_write_kernel<<<SCAN_BLOCKS, tb, 0, stream>>>(counts, partials, offs, dinv, n);
    scatter_kernel<<<(e + tb - 1) / tb, tb, 0, stream>>>(src, dst, offs, fill, dinv,
                                                         csr_col, csr_val, e);

    int gblocks = (n + 63) / 64;
    int ablocks = (n + 3) / 4;

    // layer 1 (b1/b2 dropped: BN cancels constant shift)
    gemm128_kernel<<<gblocks, tb, 0, stream>>>(x, W1, Hb, n);
    aggregate128_kernel<<<ablocks, tb, 0, stream>>>(Hb, offs, csr_col, csr_val, dinv, bufA, n);
    bn_stats_kernel<<<256, tb, 0, stream>>>(bufA, stats, n);
    bn_apply_relu_kernel<<<(n * 32 + tb - 1) / tb, tb, 0, stream>>>(bufA, stats, g1, bt1, bufB,
                                                                    n, 1.0f / n);
    // layer 2
    gemm128_kernel<<<gblocks, tb, 0, stream>>>(bufB, W2, Hb, n);
    aggregate128_kernel<<<ablocks, tb, 0, stream>>>(Hb, offs, csr_col, csr_val, dinv, bufA, n);
    bn_stats_kernel<<<256, tb, 0, stream>>>(bufA, stats + 256, n);
    bn_apply_relu_bf16_kernel<<<(n * 32 + tb - 1) / tb, tb, 0, stream>>>(bufA, stats + 256, g2,
                                                                         bt2, Hb, n, 1.0f / n);
    // layer 3 reordered: A·(H W3) = (A·H)·W3 — aggregate at 128 wide, then GEMM+lsm
    aggregate128_kernel<<<ablocks, tb, 0, stream>>>(Hb, offs, csr_col, csr_val, dinv, bufB, n);
    gemm40_lsm_kernel<<<gblocks, tb, 0, stream>>>(bufB, W3, b3, (float*)d_out, n);
}

// Round 5
// 305.919 us; speedup vs baseline: 1.7604x; 1.2777x over previous
//
#include <hip/hip_runtime.h>
#include <hip/hip_bf16.h>

#define EPS 1e-5f
#define SCAN_BLOCKS 256

typedef __attribute__((ext_vector_type(8))) short bf16x8;
typedef __attribute__((ext_vector_type(4))) float f32x4;

__device__ inline float bf2f(unsigned short u) {
    union { unsigned int i; float f; } v;
    v.i = ((unsigned int)u) << 16;
    return v.f;
}

__device__ inline unsigned short f2bf(float f) {
    union { float f; unsigned int i; } v;
    v.f = f;
    unsigned int x = v.i;
    unsigned int rounded = x + 0x7FFF + ((x >> 16) & 1);   // RNE
    return (unsigned short)(rounded >> 16);
}

// ---------------------------------------------------------------- degree/CSR

__global__ void count_kernel(const int* __restrict__ dst, int* __restrict__ counts, int e) {
    int i = blockIdx.x * blockDim.x + threadIdx.x;
    if (i < e) atomicAdd(&counts[dst[i]], 1);
}

__global__ __launch_bounds__(256) void scan_partial_kernel(const int* __restrict__ counts,
                                                           int* __restrict__ partials, int n) {
    __shared__ int sh[256];
    int chunk = (n + gridDim.x - 1) / gridDim.x;
    int lo = blockIdx.x * chunk;
    int hi = lo + chunk; if (hi > n) hi = n;
    int s = 0;
    for (int i = lo + threadIdx.x; i < hi; i += 256) s += counts[i];
    sh[threadIdx.x] = s;
    __syncthreads();
    for (int d = 128; d; d >>= 1) {
        if (threadIdx.x < d) sh[threadIdx.x] += sh[threadIdx.x + d];
        __syncthreads();
    }
    if (threadIdx.x == 0) partials[blockIdx.x] = sh[0];
}

__global__ __launch_bounds__(256) void scan_level2_kernel(int* __restrict__ partials) {
    __shared__ int sh[256];
    int t = threadIdx.x;
    sh[t] = partials[t];
    __syncthreads();
    for (int d = 1; d < 256; d <<= 1) {
        int v = (t >= d) ? sh[t - d] : 0;
        __syncthreads();
        sh[t] += v;
        __syncthreads();
    }
    partials[t] = (t == 0) ? 0 : sh[t - 1];
}

__global__ __launch_bounds__(256) void scan_write_kernel(const int* __restrict__ counts,
                                                         const int* __restrict__ partials,
                                                         int* __restrict__ offs,
                                                         float* __restrict__ dinv, int n) {
    __shared__ int sh[256];
    int t = threadIdx.x;
    int chunk = (n + gridDim.x - 1) / gridDim.x;
    int lo = blockIdx.x * chunk;
    int hi = lo + chunk; if (hi > n) hi = n;
    int per = (chunk + 255) / 256;
    int tlo = lo + t * per;
    int thi = tlo + per; if (thi > hi) thi = hi;
    int s = 0;
    for (int i = tlo; i < thi; ++i) s += counts[i];
    sh[t] = s;
    __syncthreads();
    for (int d = 1; d < 256; d <<= 1) {
        int v = (t >= d) ? sh[t - d] : 0;
        __syncthreads();
        sh[t] += v;
        __syncthreads();
    }
    int run = partials[blockIdx.x] + ((t == 0) ? 0 : sh[t - 1]);
    for (int i = tlo; i < thi; ++i) {
        offs[i] = run;
        run += counts[i];
        dinv[i] = rsqrtf((float)(counts[i] + 1));  // +1 self loop
    }
    if (tlo < n && thi == n) offs[n] = run;
}

__global__ void scatter_kernel(const int* __restrict__ src, const int* __restrict__ dst,
                               const int* __restrict__ offs, int* __restrict__ fill,
                               const float* __restrict__ dinv,
                               int* __restrict__ csr_col, float* __restrict__ csr_val, int e) {
    int i = blockIdx.x * blockDim.x + threadIdx.x;
    if (i >= e) return;
    int s = src[i], d = dst[i];
    int pos = offs[d] + atomicAdd(&fill[d], 1);
    csr_col[pos] = s;
    csr_val[pos] = dinv[s] * dinv[d];
}

// ---------------------------------------------------------------- weight prep
// WT1/WT2: [col][k] bf16 (transposed 128x128); WT3: [col(48, zero-pad)][k] bf16
__global__ void prep_weights_kernel(const float* __restrict__ W1, const float* __restrict__ W2,
                                    const float* __restrict__ W3,
                                    unsigned short* __restrict__ WT1,
                                    unsigned short* __restrict__ WT2,
                                    unsigned short* __restrict__ WT3) {
    int i = blockIdx.x * blockDim.x + threadIdx.x;
    if (i < 16384) {
        int col = i >> 7, k = i & 127;
        WT1[i] = f2bf(W1[k * 128 + col]);
    } else if (i < 32768) {
        int j = i - 16384;
        int col = j >> 7, k = j & 127;
        WT2[j] = f2bf(W2[k * 128 + col]);
    } else if (i < 32768 + 6144) {
        int j = i - 32768;
        int col = j >> 7, k = j & 127;
        WT3[j] = (col < 40) ? f2bf(W3[k * 40 + col]) : 0;
    }
}

// ---------------------------------------------------------------- MFMA GEMM 128x128
// C[n,128](bf16) = act(A[n,128](f32)) @ W; W given as WT[col][k] bf16.
// BN=true: apply BatchNorm(stats,gamma,beta)+ReLU to A during staging.
// LDS XOR-swizzle byte^((row&7)<<4) on 256-B rows (G4: avoids 16-way conflicts).
template<bool BN>
__global__ __launch_bounds__(256) void gemm128_mfma_kernel(
    const float* __restrict__ A, const unsigned short* __restrict__ WT,
    const float* __restrict__ stats, const float* __restrict__ gamma,
    const float* __restrict__ beta, float invn,
    unsigned short* __restrict__ C, int n) {
    __shared__ unsigned short lW[128 * 128];  // 32 KB [col][k] swizzled
    __shared__ unsigned short lA[64 * 128];   // 16 KB [row][k] swizzled
    int tid = threadIdx.x;
    const uint4* wsrc = (const uint4*)WT;
#pragma unroll
    for (int it = 0; it < 8; ++it) {
        int idx = tid + it * 256;
        int byte = idx << 4;
        int dst = byte ^ (((byte >> 8) & 7) << 4);
        *(uint4*)((char*)lW + dst) = wsrc[idx];
    }
    int row0 = blockIdx.x * 64;
#pragma unroll
    for (int it = 0; it < 4; ++it) {
        int idx = tid + it * 256;   // 16-B chunk (8 bf16) in lA
        int r = idx >> 4;
        int cc = (idx & 15) << 3;
        int gr = row0 + r; if (gr > n - 1) gr = n - 1;   // dup rows masked on write
        const float* ap = A + (size_t)gr * 128 + cc;
        float4 f0 = *(const float4*)ap;
        float4 f1 = *(const float4*)(ap + 4);
        float v[8] = {f0.x, f0.y, f0.z, f0.w, f1.x, f1.y, f1.z, f1.w};
        union { unsigned short u[8]; uint4 q; } t;
#pragma unroll
        for (int j = 0; j < 8; ++j) {
            float x = v[j];
            if (BN) {
                int c = cc + j;
                float mu = stats[c] * invn;
                float var = stats[128 + c] * invn - mu * mu;
                float sc = gamma[c] * rsqrtf(var + EPS);
                float sh = beta[c] - mu * sc;
                x = fmaf(x, sc, sh);
                x = x > 0.0f ? x : 0.0f;
            }
            t.u[j] = f2bf(x);
        }
        int byte = idx << 4;
        int dst = byte ^ (((byte >> 8) & 7) << 4);
        *(uint4*)((char*)lA + dst) = t.q;
    }
    __syncthreads();

    int lane = tid & 63;
    int mrow0 = (tid >> 6) << 4;            // wave's 16 rows
    int arow = mrow0 + (lane & 15);
    int swz = (lane & 7) << 4;              // (row&7)<<4 == (col&7)<<4 == (lane&7)<<4
    int koff = (lane >> 4) << 4;            // k byte offset for this lane group
    const char* pA = (const char*)lA + (arow << 8);
    const char* pB = (const char*)lW + ((lane & 15) << 8);
    f32x4 acc[8];
#pragma unroll
    for (int t8 = 0; t8 < 8; ++t8) acc[t8] = (f32x4){0.f, 0.f, 0.f, 0.f};
#pragma unroll
    for (int kk = 0; kk < 4; ++kk) {
        int kb = (kk << 6) + koff;
        bf16x8 af = *(const bf16x8*)(pA + (kb ^ swz));
#pragma unroll
        for (int t8 = 0; t8 < 8; ++t8) {
            bf16x8 bf = *(const bf16x8*)(pB + (t8 << 12) + (kb ^ swz));
            acc[t8] = __builtin_amdgcn_mfma_f32_16x16x32_bf16(af, bf, acc[t8], 0, 0, 0);
        }
    }
    // C layout: row=(lane>>4)*4+j, col=lane&15 (m89-verified)
    int crow = row0 + mrow0 + ((lane >> 4) << 2);
    int ccol = lane & 15;
    unsigned short* cp = C + (size_t)crow * 128 + ccol;
#pragma unroll
    for (int j = 0; j < 4; ++j) {
        if (crow + j < n) {
#pragma unroll
            for (int t8 = 0; t8 < 8; ++t8)
                cp[(size_t)j * 128 + t8 * 16] = f2bf(acc[t8][j]);
        }
    }
}

// ---------------------------------------------------------------- MFMA GEMM 128x40 + log_softmax
// out[n,40](f32) = log_softmax(A[n,128](bf16) @ W3 + b3)
__global__ __launch_bounds__(256) void gemm40_lsm_mfma_kernel(
    const unsigned short* __restrict__ A, const unsigned short* __restrict__ WT,
    const float* __restrict__ b3, float* __restrict__ out, int n) {
    __shared__ unsigned short lW[48 * 128];   // 12 KB
    __shared__ unsigned short lA[64 * 128];   // 16 KB
    __shared__ float sRow[64 * 49];
    __shared__ float sD[64];
    __shared__ float sB[48];
    int tid = threadIdx.x;
    if (tid < 48) sB[tid] = (tid < 40) ? b3[tid] : 0.0f;
    const uint4* wsrc = (const uint4*)WT;
#pragma unroll
    for (int it = 0; it < 3; ++it) {
        int idx = tid + it * 256;
        int byte = idx << 4;
        int dst = byte ^ (((byte >> 8) & 7) << 4);
        *(uint4*)((char*)lW + dst) = wsrc[idx];
    }
    int row0 = blockIdx.x * 64;
#pragma unroll
    for (int it = 0; it < 4; ++it) {
        int idx = tid + it * 256;
        int r = idx >> 4;
        int cc = (idx & 15) << 3;
        int gr = row0 + r; if (gr > n - 1) gr = n - 1;
        uint4 q = *(const uint4*)(A + (size_t)gr * 128 + cc);
        int byte = idx << 4;
        int dst = byte ^ (((byte >> 8) & 7) << 4);
        *(uint4*)((char*)lA + dst) = q;
    }
    __syncthreads();

    int lane = tid & 63;
    int mrow0 = (tid >> 6) << 4;
    int arow = mrow0 + (lane & 15);
    int swz = (lane & 7) << 4;
    int koff = (lane >> 4) << 4;
    const char* pA = (const char*)lA + (arow << 8);
    const char* pB = (const char*)lW + ((lane & 15) << 8);
    f32x4 acc[3];
#pragma unroll
    for (int t8 = 0; t8 < 3; ++t8) acc[t8] = (f32x4){0.f, 0.f, 0.f, 0.f};
#pragma unroll
    for (int kk = 0; kk < 4; ++kk) {
        int kb = (kk << 6) + koff;
        bf16x8 af = *(const bf16x8*)(pA + (kb ^ swz));
#pragma unroll
        for (int t8 = 0; t8 < 3; ++t8) {
            bf16x8 bf = *(const bf16x8*)(pB + (t8 << 12) + (kb ^ swz));
            acc[t8] = __builtin_amdgcn_mfma_f32_16x16x32_bf16(af, bf, acc[t8], 0, 0, 0);
        }
    }
    int lrow = mrow0 + ((lane >> 4) << 2);
    int ccol = lane & 15;
#pragma unroll
    for (int t8 = 0; t8 < 3; ++t8)
#pragma unroll
        for (int j = 0; j < 4; ++j)
            sRow[(lrow + j) * 49 + t8 * 16 + ccol] = acc[t8][j] + sB[t8 * 16 + ccol];
    __syncthreads();
    if (tid < 64) {
        float m = -1e30f;
        for (int c = 0; c < 40; ++c) m = fmaxf(m, sRow[tid * 49 + c]);
        float l = 0.0f;
        for (int c = 0; c < 40; ++c) l += expf(sRow[tid * 49 + c] - m);
        sD[tid] = m + logf(l);
    }
    __syncthreads();
    for (int i = tid; i < 64 * 40; i += 256) {
        int r = i / 40;
        int c = i - r * 40;
        int gr = row0 + r;
        if (gr < n) out[(size_t)gr * 40 + c] = sRow[r * 49 + c] - sD[r];
    }
}

// ---------------------------------------------------------------- aggregation

// out[node,:] = dinv^2 * H[node,:] + sum_e vals[e]*H[cols[e],:], H bf16
// one 64-lane wave per node; OUT16: write bf16 (packed dword) else f32
template<bool OUT16>
__global__ __launch_bounds__(256) void aggregate128_kernel(
    const unsigned short* __restrict__ H, const int* __restrict__ offs,
    const int* __restrict__ cols, const float* __restrict__ vals,
    const float* __restrict__ dinv, void* __restrict__ outp, int n) {
    int node = (blockIdx.x * blockDim.x + threadIdx.x) >> 6;
    if (node >= n) return;
    int lane = threadIdx.x & 63;
    float di = dinv[node];
    unsigned int h0 = *(const unsigned int*)(H + (size_t)node * 128 + lane * 2);
    float2 acc0, acc1;
    acc0.x = bf2f((unsigned short)h0) * di * di;
    acc0.y = bf2f((unsigned short)(h0 >> 16)) * di * di;
    acc1.x = 0.0f; acc1.y = 0.0f;
    int e0 = offs[node], e1 = offs[node + 1];
    int e = e0;
    for (; e + 2 <= e1; e += 2) {
        int sA = cols[e], sB = cols[e + 1];
        float wA = vals[e], wB = vals[e + 1];
        unsigned int hA = *(const unsigned int*)(H + (size_t)sA * 128 + lane * 2);
        unsigned int hB = *(const unsigned int*)(H + (size_t)sB * 128 + lane * 2);
        acc0.x += bf2f((unsigned short)hA) * wA;
        acc0.y += bf2f((unsigned short)(hA >> 16)) * wA;
        acc1.x += bf2f((unsigned short)hB) * wB;
        acc1.y += bf2f((unsigned short)(hB >> 16)) * wB;
    }
    if (e < e1) {
        int sA = cols[e];
        float wA = vals[e];
        unsigned int hA = *(const unsigned int*)(H + (size_t)sA * 128 + lane * 2);
        acc0.x += bf2f((unsigned short)hA) * wA;
        acc0.y += bf2f((unsigned short)(hA >> 16)) * wA;
    }
    acc0.x += acc1.x;
    acc0.y += acc1.y;
    if (OUT16) {
        unsigned int pack = (unsigned int)f2bf(acc0.x) | ((unsigned int)f2bf(acc0.y) << 16);
        *(unsigned int*)((unsigned short*)outp + (size_t)node * 128 + lane * 2) = pack;
    } else {
        *(float2*)((float*)outp + (size_t)node * 128 + lane * 2) = acc0;
    }
}

// ---------------------------------------------------------------- batchnorm

__global__ __launch_bounds__(256) void bn_stats_kernel(const float* __restrict__ X,
                                                       float* __restrict__ stats, int n) {
    int tid = threadIdx.x;
    int c = tid & 127;
    int r0 = blockIdx.x * 2 + (tid >> 7);
    float s = 0.0f, q = 0.0f;
    for (int r = r0; r < n; r += gridDim.x * 2) {
        float v = X[(size_t)r * 128 + c];
        s += v;
        q += v * v;
    }
    __shared__ float sh[256], shq[256];
    sh[tid] = s; shq[tid] = q;
    __syncthreads();
    if (tid < 128) {
        atomicAdd(&stats[c], sh[tid] + sh[tid + 128]);
        atomicAdd(&stats[128 + c], shq[tid] + shq[tid + 128]);
    }
}

// bf16 output (feeds final aggregation gather)
__global__ void bn_apply_relu_bf16_kernel(const float* __restrict__ X,
                                          const float* __restrict__ stats,
                                          const float* __restrict__ gamma,
                                          const float* __restrict__ beta,
                                          unsigned short* __restrict__ Y, int n, float invn) {
    int i = blockIdx.x * blockDim.x + threadIdx.x;
    int total = n * 32;  // float4s
    if (i >= total) return;
    int c0 = (i & 31) * 4;
    float4 x = ((const float4*)X)[i];
    float xv[4] = {x.x, x.y, x.z, x.w};
    ushort4 o;
    unsigned short ov[4];
#pragma unroll
    for (int j = 0; j < 4; ++j) {
        int c = c0 + j;
        float mu = stats[c] * invn;
        float var = stats[128 + c] * invn - mu * mu;
        float sc = gamma[c] * rsqrtf(var + EPS);
        float sh = beta[c] - mu * sc;
        float v = fmaf(xv[j], sc, sh);
        ov[j] = f2bf(v > 0.0f ? v : 0.0f);
    }
    o.x = ov[0]; o.y = ov[1]; o.z = ov[2]; o.w = ov[3];
    ((ushort4*)Y)[i] = o;
}

// ---------------------------------------------------------------- launch

extern "C" void kernel_launch(void* const* d_in, const int* in_sizes, int n_in,
                              void* d_out, int out_size, void* d_ws, size_t ws_size,
                              hipStream_t stream) {
    const float* x   = (const float*)d_in[0];
    const int*   ei  = (const int*)d_in[1];
    const float* W1  = (const float*)d_in[2];
    const float* g1  = (const float*)d_in[4];
    const float* bt1 = (const float*)d_in[5];
    const float* W2  = (const float*)d_in[6];
    const float* g2  = (const float*)d_in[8];
    const float* bt2 = (const float*)d_in[9];
    const float* W3  = (const float*)d_in[10];
    const float* b3  = (const float*)d_in[11];

    int n = in_sizes[0] / 128;
    int e = in_sizes[1] / 2;
    const int* src = ei;
    const int* dst = ei + e;

    char* p = (char*)d_ws;
    auto alloc = [&](size_t bytes) -> char* {
        char* q = p;
        p += (bytes + 255) & ~(size_t)255;
        return q;
    };
    int*            counts   = (int*)alloc((size_t)n * 4);
    int*            offs     = (int*)alloc((size_t)(n + 1) * 4);
    int*            fill     = (int*)alloc((size_t)n * 4);
    float*          dinv     = (float*)alloc((size_t)n * 4);
    int*            partials = (int*)alloc(SCAN_BLOCKS * 4);
    int*            csr_col  = (int*)alloc((size_t)e * 4);
    float*          csr_val  = (float*)alloc((size_t)e * 4);
    float*          stats    = (float*)alloc(512 * 4);
    unsigned short* WT1      = (unsigned short*)alloc(16384 * 2);
    unsigned short* WT2      = (unsigned short*)alloc(16384 * 2);
    unsigned short* WT3      = (unsigned short*)alloc(6144 * 2);
    unsigned short* Hb       = (unsigned short*)alloc((size_t)n * 128 * 2);
    unsigned short* Hb2      = (unsigned short*)alloc((size_t)n * 128 * 2);
    float*          bufA     = (float*)alloc((size_t)n * 128 * 4);

    hipMemsetAsync(counts, 0, (size_t)n * 4, stream);
    hipMemsetAsync(fill, 0, (size_t)n * 4, stream);
    hipMemsetAsync(stats, 0, 512 * 4, stream);

    const int tb = 256;
    float invn = 1.0f / n;
    prep_weights_kernel<<<(38912 + tb - 1) / tb, tb, 0, stream>>>(W1, W2, W3, WT1, WT2, WT3);
    count_kernel<<<(e + tb - 1) / tb, tb, 0, stream>>>(dst, counts, e);
    scan_partial_kernel<<<SCAN_BLOCKS, tb, 0, stream>>>(counts, partials, n);
    scan_level2_kernel<<<1, tb, 0, stream>>>(partials);
    scan_write_kernel<<<SCAN_BLOCKS, tb, 0, stream>>>(counts, partials, offs, dinv, n);
    scatter_kernel<<<(e + tb - 1) / tb, tb, 0, stream>>>(src, dst, offs, fill, dinv,
                                                         csr_col, csr_val, e);

    int gblocks = (n + 63) / 64;
    int ablocks = (n + 3) / 4;

    // layer 1 (b1/b2 dropped: BN cancels constant shift)
    gemm128_mfma_kernel<false><<<gblocks, tb, 0, stream>>>(x, WT1, nullptr, nullptr, nullptr,
                                                           0.0f, Hb, n);
    aggregate128_kernel<false><<<ablocks, tb, 0, stream>>>(Hb, offs, csr_col, csr_val, dinv,
                                                           bufA, n);
    bn_stats_kernel<<<256, tb, 0, stream>>>(bufA, stats, n);
    // layer 2: BN1+ReLU fused into A-staging
    gemm128_mfma_kernel<true><<<gblocks, tb, 0, stream>>>(bufA, WT2, stats, g1, bt1, invn,
                                                          Hb, n);
    aggregate128_kernel<false><<<ablocks, tb, 0, stream>>>(Hb, offs, csr_col, csr_val, dinv,
                                                           bufA, n);
    bn_stats_kernel<<<256, tb, 0, stream>>>(bufA, stats + 256, n);
    bn_apply_relu_bf16_kernel<<<(n * 32 + tb - 1) / tb, tb, 0, stream>>>(bufA, stats + 256, g2,
                                                                         bt2, Hb, n, invn);
    // layer 3: aggregate first (A·(H W3) = (A·H)·W3), then GEMM + fused log_softmax
    aggregate128_kernel<true><<<ablocks, tb, 0, stream>>>(Hb, offs, csr_col, csr_val, dinv,
                                                          Hb2, n);
    gemm40_lsm_mfma_kernel<<<gblocks, tb, 0, stream>>>(Hb2, WT3, b3, (float*)d_out, n);
}

// Round 6
// 269.126 us; speedup vs baseline: 2.0011x; 1.1367x over previous
//
#include <hip/hip_runtime.h>
#include <hip/hip_bf16.h>

#define EPS 1e-5f
#define SCAN_BLOCKS 256

typedef __attribute__((ext_vector_type(8))) short bf16x8;
typedef __attribute__((ext_vector_type(4))) float f32x4;

__device__ inline float bf2f(unsigned short u) {
    union { unsigned int i; float f; } v;
    v.i = ((unsigned int)u) << 16;
    return v.f;
}

__device__ inline unsigned short f2bf(float f) {
    union { float f; unsigned int i; } v;
    v.f = f;
    unsigned int x = v.i;
    unsigned int rounded = x + 0x7FFF + ((x >> 16) & 1);   // RNE
    return (unsigned short)(rounded >> 16);
}

// ---------------------------------------------------------------- degree/CSR

__global__ void count_kernel(const int* __restrict__ dst, int* __restrict__ counts, int e) {
    int i = blockIdx.x * blockDim.x + threadIdx.x;
    if (i < e) atomicAdd(&counts[dst[i]], 1);
}

__global__ __launch_bounds__(256) void scan_partial_kernel(const int* __restrict__ counts,
                                                           int* __restrict__ partials, int n) {
    __shared__ int sh[256];
    int chunk = (n + gridDim.x - 1) / gridDim.x;
    int lo = blockIdx.x * chunk;
    int hi = lo + chunk; if (hi > n) hi = n;
    int s = 0;
    for (int i = lo + threadIdx.x; i < hi; i += 256) s += counts[i];
    sh[threadIdx.x] = s;
    __syncthreads();
    for (int d = 128; d; d >>= 1) {
        if (threadIdx.x < d) sh[threadIdx.x] += sh[threadIdx.x + d];
        __syncthreads();
    }
    if (threadIdx.x == 0) partials[blockIdx.x] = sh[0];
}

__global__ __launch_bounds__(256) void scan_level2_kernel(int* __restrict__ partials) {
    __shared__ int sh[256];
    int t = threadIdx.x;
    sh[t] = partials[t];
    __syncthreads();
    for (int d = 1; d < 256; d <<= 1) {
        int v = (t >= d) ? sh[t - d] : 0;
        __syncthreads();
        sh[t] += v;
        __syncthreads();
    }
    partials[t] = (t == 0) ? 0 : sh[t - 1];
}

__global__ __launch_bounds__(256) void scan_write_kernel(const int* __restrict__ counts,
                                                         const int* __restrict__ partials,
                                                         int* __restrict__ offs,
                                                         float* __restrict__ dinv, int n) {
    __shared__ int sh[256];
    int t = threadIdx.x;
    int chunk = (n + gridDim.x - 1) / gridDim.x;
    int lo = blockIdx.x * chunk;
    int hi = lo + chunk; if (hi > n) hi = n;
    int per = (chunk + 255) / 256;
    int tlo = lo + t * per;
    int thi = tlo + per; if (thi > hi) thi = hi;
    int s = 0;
    for (int i = tlo; i < thi; ++i) s += counts[i];
    sh[t] = s;
    __syncthreads();
    for (int d = 1; d < 256; d <<= 1) {
        int v = (t >= d) ? sh[t - d] : 0;
        __syncthreads();
        sh[t] += v;
        __syncthreads();
    }
    int run = partials[blockIdx.x] + ((t == 0) ? 0 : sh[t - 1]);
    for (int i = tlo; i < thi; ++i) {
        offs[i] = run;
        run += counts[i];
        dinv[i] = rsqrtf((float)(counts[i] + 1));  // +1 self loop
    }
    if (tlo < n && thi == n) offs[n] = run;
}

// csr[pos] = (src, bitcast(norm))
__global__ void scatter_kernel(const int* __restrict__ src, const int* __restrict__ dst,
                               const int* __restrict__ offs, int* __restrict__ fill,
                               const float* __restrict__ dinv,
                               int2* __restrict__ csr, int e) {
    int i = blockIdx.x * blockDim.x + threadIdx.x;
    if (i >= e) return;
    int s = src[i], d = dst[i];
    int pos = offs[d] + atomicAdd(&fill[d], 1);
    float w = dinv[s] * dinv[d];
    csr[pos] = make_int2(s, __float_as_int(w));
}

// ---------------------------------------------------------------- weight prep
// WT1/WT2: [col][k] bf16 (transposed 128x128); WT3: [col(48, zero-pad)][k] bf16
__global__ void prep_weights_kernel(const float* __restrict__ W1, const float* __restrict__ W2,
                                    const float* __restrict__ W3,
                                    unsigned short* __restrict__ WT1,
                                    unsigned short* __restrict__ WT2,
                                    unsigned short* __restrict__ WT3) {
    int i = blockIdx.x * blockDim.x + threadIdx.x;
    if (i < 16384) {
        int col = i >> 7, k = i & 127;
        WT1[i] = f2bf(W1[k * 128 + col]);
    } else if (i < 32768) {
        int j = i - 16384;
        int col = j >> 7, k = j & 127;
        WT2[j] = f2bf(W2[k * 128 + col]);
    } else if (i < 32768 + 6144) {
        int j = i - 32768;
        int col = j >> 7, k = j & 127;
        WT3[j] = (col < 40) ? f2bf(W3[k * 40 + col]) : 0;
    }
}

// ---------------------------------------------------------------- MFMA GEMM 128x128
// C[n,128](bf16) = act(A[n,128]) @ W; W given as WT[col][k] bf16.
// MODE 0: A f32, no BN (layer 1). MODE 1: A bf16, BN(stats,gamma,beta)+ReLU in staging.
// LDS XOR-swizzle byte^((row&7)<<4) on 256-B rows.
template<int MODE>
__global__ __launch_bounds__(256) void gemm128_mfma_kernel(
    const void* __restrict__ Aptr, const unsigned short* __restrict__ WT,
    const float* __restrict__ stats, const float* __restrict__ gamma,
    const float* __restrict__ beta, float invn,
    unsigned short* __restrict__ C, int n) {
    __shared__ unsigned short lW[128 * 128];  // 32 KB [col][k] swizzled
    __shared__ unsigned short lA[64 * 128];   // 16 KB [row][k] swizzled
    __shared__ float scs[128], shs[128];
    int tid = threadIdx.x;
    if (MODE == 1) {
        if (tid < 128) {
            float mu = stats[tid] * invn;
            float var = stats[128 + tid] * invn - mu * mu;
            float sc = gamma[tid] * rsqrtf(var + EPS);
            scs[tid] = sc;
            shs[tid] = beta[tid] - mu * sc;
        }
        __syncthreads();
    }
    const uint4* wsrc = (const uint4*)WT;
#pragma unroll
    for (int it = 0; it < 8; ++it) {
        int idx = tid + it * 256;
        int byte = idx << 4;
        int dst = byte ^ (((byte >> 8) & 7) << 4);
        *(uint4*)((char*)lW + dst) = wsrc[idx];
    }
    int row0 = blockIdx.x * 64;
#pragma unroll
    for (int it = 0; it < 4; ++it) {
        int idx = tid + it * 256;   // 16-B chunk (8 bf16) in lA
        int r = idx >> 4;
        int cc = (idx & 15) << 3;
        int gr = row0 + r; if (gr > n - 1) gr = n - 1;   // dup rows masked on write
        union { unsigned short u[8]; uint4 q; } t;
        if (MODE == 0) {
            const float* ap = (const float*)Aptr + (size_t)gr * 128 + cc;
            float4 f0 = *(const float4*)ap;
            float4 f1 = *(const float4*)(ap + 4);
            float v[8] = {f0.x, f0.y, f0.z, f0.w, f1.x, f1.y, f1.z, f1.w};
#pragma unroll
            for (int j = 0; j < 8; ++j) t.u[j] = f2bf(v[j]);
        } else {
            uint4 q = *(const uint4*)((const unsigned short*)Aptr + (size_t)gr * 128 + cc);
            unsigned int w[4] = {q.x, q.y, q.z, q.w};
#pragma unroll
            for (int j = 0; j < 8; ++j) {
                float x = bf2f((unsigned short)(w[j >> 1] >> ((j & 1) * 16)));
                int c = cc + j;
                x = fmaf(x, scs[c], shs[c]);
                x = x > 0.0f ? x : 0.0f;
                t.u[j] = f2bf(x);
            }
        }
        int byte = idx << 4;
        int dst = byte ^ (((byte >> 8) & 7) << 4);
        *(uint4*)((char*)lA + dst) = t.q;
    }
    __syncthreads();

    int lane = tid & 63;
    int mrow0 = (tid >> 6) << 4;            // wave's 16 rows
    int arow = mrow0 + (lane & 15);
    int swz = (lane & 7) << 4;
    int koff = (lane >> 4) << 4;
    const char* pA = (const char*)lA + (arow << 8);
    const char* pB = (const char*)lW + ((lane & 15) << 8);
    f32x4 acc[8];
#pragma unroll
    for (int t8 = 0; t8 < 8; ++t8) acc[t8] = (f32x4){0.f, 0.f, 0.f, 0.f};
#pragma unroll
    for (int kk = 0; kk < 4; ++kk) {
        int kb = (kk << 6) + koff;
        bf16x8 af = *(const bf16x8*)(pA + (kb ^ swz));
#pragma unroll
        for (int t8 = 0; t8 < 8; ++t8) {
            bf16x8 bf = *(const bf16x8*)(pB + (t8 << 12) + (kb ^ swz));
            acc[t8] = __builtin_amdgcn_mfma_f32_16x16x32_bf16(af, bf, acc[t8], 0, 0, 0);
        }
    }
    // C layout: row=(lane>>4)*4+j, col=lane&15 (m89-verified)
    int crow = row0 + mrow0 + ((lane >> 4) << 2);
    int ccol = lane & 15;
    unsigned short* cp = C + (size_t)crow * 128 + ccol;
#pragma unroll
    for (int j = 0; j < 4; ++j) {
        if (crow + j < n) {
#pragma unroll
            for (int t8 = 0; t8 < 8; ++t8)
                cp[(size_t)j * 128 + t8 * 16] = f2bf(acc[t8][j]);
        }
    }
}

// ---------------------------------------------------------------- MFMA GEMM 128x40 + log_softmax
__global__ __launch_bounds__(256) void gemm40_lsm_mfma_kernel(
    const unsigned short* __restrict__ A, const unsigned short* __restrict__ WT,
    const float* __restrict__ b3, float* __restrict__ out, int n) {
    __shared__ unsigned short lW[48 * 128];   // 12 KB
    __shared__ unsigned short lA[64 * 128];   // 16 KB
    __shared__ float sRow[64 * 49];
    __shared__ float sD[64];
    __shared__ float sB[48];
    int tid = threadIdx.x;
    if (tid < 48) sB[tid] = (tid < 40) ? b3[tid] : 0.0f;
    const uint4* wsrc = (const uint4*)WT;
#pragma unroll
    for (int it = 0; it < 3; ++it) {
        int idx = tid + it * 256;
        int byte = idx << 4;
        int dst = byte ^ (((byte >> 8) & 7) << 4);
        *(uint4*)((char*)lW + dst) = wsrc[idx];
    }
    int row0 = blockIdx.x * 64;
#pragma unroll
    for (int it = 0; it < 4; ++it) {
        int idx = tid + it * 256;
        int r = idx >> 4;
        int cc = (idx & 15) << 3;
        int gr = row0 + r; if (gr > n - 1) gr = n - 1;
        uint4 q = *(const uint4*)(A + (size_t)gr * 128 + cc);
        int byte = idx << 4;
        int dst = byte ^ (((byte >> 8) & 7) << 4);
        *(uint4*)((char*)lA + dst) = q;
    }
    __syncthreads();

    int lane = tid & 63;
    int mrow0 = (tid >> 6) << 4;
    int arow = mrow0 + (lane & 15);
    int swz = (lane & 7) << 4;
    int koff = (lane >> 4) << 4;
    const char* pA = (const char*)lA + (arow << 8);
    const char* pB = (const char*)lW + ((lane & 15) << 8);
    f32x4 acc[3];
#pragma unroll
    for (int t8 = 0; t8 < 3; ++t8) acc[t8] = (f32x4){0.f, 0.f, 0.f, 0.f};
#pragma unroll
    for (int kk = 0; kk < 4; ++kk) {
        int kb = (kk << 6) + koff;
        bf16x8 af = *(const bf16x8*)(pA + (kb ^ swz));
#pragma unroll
        for (int t8 = 0; t8 < 3; ++t8) {
            bf16x8 bf = *(const bf16x8*)(pB + (t8 << 12) + (kb ^ swz));
            acc[t8] = __builtin_amdgcn_mfma_f32_16x16x32_bf16(af, bf, acc[t8], 0, 0, 0);
        }
    }
    int lrow = mrow0 + ((lane >> 4) << 2);
    int ccol = lane & 15;
#pragma unroll
    for (int t8 = 0; t8 < 3; ++t8)
#pragma unroll
        for (int j = 0; j < 4; ++j)
            sRow[(lrow + j) * 49 + t8 * 16 + ccol] = acc[t8][j] + sB[t8 * 16 + ccol];
    __syncthreads();
    if (tid < 64) {
        float m = -1e30f;
        for (int c = 0; c < 40; ++c) m = fmaxf(m, sRow[tid * 49 + c]);
        float l = 0.0f;
        for (int c = 0; c < 40; ++c) l += expf(sRow[tid * 49 + c] - m);
        sD[tid] = m + logf(l);
    }
    __syncthreads();
    for (int i = tid; i < 64 * 40; i += 256) {
        int r = i / 40;
        int c = i - r * 40;
        int gr = row0 + r;
        if (gr < n) out[(size_t)gr * 40 + c] = sRow[r * 49 + c] - sD[r];
    }
}

// ---------------------------------------------------------------- aggregation

// out[node,:](bf16) = dinv^2*act(H[node,:]) + sum_e w_e*act(H[col_e,:]), H bf16
// BN=true: act = relu(bn(.)) fused per gathered element (sc/sh precomputed per lane).
// one 64-lane wave per node, 4-edge unroll (4 gathers in flight).
template<bool BN>
__global__ __launch_bounds__(256) void aggregate128_kernel(
    const unsigned short* __restrict__ H, const int* __restrict__ offs,
    const int2* __restrict__ csr, const float* __restrict__ dinv,
    const float* __restrict__ stats, const float* __restrict__ gamma,
    const float* __restrict__ beta, float invn,
    unsigned short* __restrict__ out, int n) {
    int node = (blockIdx.x * blockDim.x + threadIdx.x) >> 6;
    if (node >= n) return;
    int lane = threadIdx.x & 63;
    int c0 = lane * 2;
    float sc0 = 1.0f, sh0 = 0.0f, sc1 = 1.0f, sh1 = 0.0f;
    if (BN) {
        float mu0 = stats[c0] * invn;
        float var0 = stats[128 + c0] * invn - mu0 * mu0;
        sc0 = gamma[c0] * rsqrtf(var0 + EPS);
        sh0 = beta[c0] - mu0 * sc0;
        float mu1 = stats[c0 + 1] * invn;
        float var1 = stats[128 + c0 + 1] * invn - mu1 * mu1;
        sc1 = gamma[c0 + 1] * rsqrtf(var1 + EPS);
        sh1 = beta[c0 + 1] - mu1 * sc1;
    }
    auto loadf = [&](int row) -> float2 {
        unsigned int hv = *(const unsigned int*)(H + (size_t)row * 128 + c0);
        float x0 = bf2f((unsigned short)hv);
        float x1 = bf2f((unsigned short)(hv >> 16));
        if (BN) {
            x0 = fmaf(x0, sc0, sh0); x0 = x0 > 0.0f ? x0 : 0.0f;
            x1 = fmaf(x1, sc1, sh1); x1 = x1 > 0.0f ? x1 : 0.0f;
        }
        return make_float2(x0, x1);
    };
    float di = dinv[node];
    float2 self = loadf(node);
    float2 a0 = make_float2(self.x * di * di, self.y * di * di);
    float2 a1 = make_float2(0.f, 0.f), a2 = make_float2(0.f, 0.f), a3 = make_float2(0.f, 0.f);
    int e = offs[node], e1 = offs[node + 1];
    for (; e + 4 <= e1; e += 4) {
        int2 q0 = csr[e], q1 = csr[e + 1], q2 = csr[e + 2], q3 = csr[e + 3];
        float2 h0 = loadf(q0.x);
        float2 h1 = loadf(q1.x);
        float2 h2 = loadf(q2.x);
        float2 h3 = loadf(q3.x);
        float w0 = __int_as_float(q0.y), w1 = __int_as_float(q1.y);
        float w2 = __int_as_float(q2.y), w3 = __int_as_float(q3.y);
        a0.x = fmaf(h0.x, w0, a0.x); a0.y = fmaf(h0.y, w0, a0.y);
        a1.x = fmaf(h1.x, w1, a1.x); a1.y = fmaf(h1.y, w1, a1.y);
        a2.x = fmaf(h2.x, w2, a2.x); a2.y = fmaf(h2.y, w2, a2.y);
        a3.x = fmaf(h3.x, w3, a3.x); a3.y = fmaf(h3.y, w3, a3.y);
    }
    for (; e < e1; ++e) {
        int2 q = csr[e];
        float2 h = loadf(q.x);
        float w = __int_as_float(q.y);
        a0.x = fmaf(h.x, w, a0.x); a0.y = fmaf(h.y, w, a0.y);
    }
    float rx = (a0.x + a1.x) + (a2.x + a3.x);
    float ry = (a0.y + a1.y) + (a2.y + a3.y);
    unsigned int pack = (unsigned int)f2bf(rx) | ((unsigned int)f2bf(ry) << 16);
    *(unsigned int*)(out + (size_t)node * 128 + c0) = pack;
}

// ---------------------------------------------------------------- batchnorm stats (bf16 in)

__global__ __launch_bounds__(256) void bn_stats_kernel(const unsigned short* __restrict__ X,
                                                       float* __restrict__ stats, int n) {
    int tid = threadIdx.x;
    int c = tid & 127;
    int r0 = blockIdx.x * 2 + (tid >> 7);
    float s = 0.0f, q = 0.0f;
    for (int r = r0; r < n; r += gridDim.x * 2) {
        float v = bf2f(X[(size_t)r * 128 + c]);
        s += v;
        q += v * v;
    }
    __shared__ float sh[256], shq[256];
    sh[tid] = s; shq[tid] = q;
    __syncthreads();
    if (tid < 128) {
        atomicAdd(&stats[c], sh[tid] + sh[tid + 128]);
        atomicAdd(&stats[128 + c], shq[tid] + shq[tid + 128]);
    }
}

// ---------------------------------------------------------------- launch

extern "C" void kernel_launch(void* const* d_in, const int* in_sizes, int n_in,
                              void* d_out, int out_size, void* d_ws, size_t ws_size,
                              hipStream_t stream) {
    const float* x   = (const float*)d_in[0];
    const int*   ei  = (const int*)d_in[1];
    const float* W1  = (const float*)d_in[2];
    const float* g1  = (const float*)d_in[4];
    const float* bt1 = (const float*)d_in[5];
    const float* W2  = (const float*)d_in[6];
    const float* g2  = (const float*)d_in[8];
    const float* bt2 = (const float*)d_in[9];
    const float* W3  = (const float*)d_in[10];
    const float* b3  = (const float*)d_in[11];

    int n = in_sizes[0] / 128;
    int e = in_sizes[1] / 2;
    const int* src = ei;
    const int* dst = ei + e;

    char* p = (char*)d_ws;
    auto alloc = [&](size_t bytes) -> char* {
        char* q = p;
        p += (bytes + 255) & ~(size_t)255;
        return q;
    };
    int*            counts   = (int*)alloc((size_t)n * 4);
    int*            offs     = (int*)alloc((size_t)(n + 1) * 4);
    int*            fill     = (int*)alloc((size_t)n * 4);
    float*          dinv     = (float*)alloc((size_t)n * 4);
    int*            partials = (int*)alloc(SCAN_BLOCKS * 4);
    int2*           csr      = (int2*)alloc((size_t)e * 8);
    float*          stats    = (float*)alloc(512 * 4);
    unsigned short* WT1      = (unsigned short*)alloc(16384 * 2);
    unsigned short* WT2      = (unsigned short*)alloc(16384 * 2);
    unsigned short* WT3      = (unsigned short*)alloc(6144 * 2);
    unsigned short* Hb       = (unsigned short*)alloc((size_t)n * 128 * 2);
    unsigned short* Ab       = (unsigned short*)alloc((size_t)n * 128 * 2);
    unsigned short* Ab2      = (unsigned short*)alloc((size_t)n * 128 * 2);
    unsigned short* Hb2      = (unsigned short*)alloc((size_t)n * 128 * 2);

    hipMemsetAsync(counts, 0, (size_t)n * 4, stream);
    hipMemsetAsync(fill, 0, (size_t)n * 4, stream);
    hipMemsetAsync(stats, 0, 512 * 4, stream);

    const int tb = 256;
    float invn = 1.0f / n;
    prep_weights_kernel<<<(38912 + tb - 1) / tb, tb, 0, stream>>>(W1, W2, W3, WT1, WT2, WT3);
    count_kernel<<<(e + tb - 1) / tb, tb, 0, stream>>>(dst, counts, e);
    scan_partial_kernel<<<SCAN_BLOCKS, tb, 0, stream>>>(counts, partials, n);
    scan_level2_kernel<<<1, tb, 0, stream>>>(partials);
    scan_write_kernel<<<SCAN_BLOCKS, tb, 0, stream>>>(counts, partials, offs, dinv, n);
    scatter_kernel<<<(e + tb - 1) / tb, tb, 0, stream>>>(src, dst, offs, fill, dinv, csr, e);

    int gblocks = (n + 63) / 64;
    int ablocks = (n + 3) / 4;

    // layer 1 (b1/b2 dropped: BN cancels constant shift)
    gemm128_mfma_kernel<0><<<gblocks, tb, 0, stream>>>(x, WT1, nullptr, nullptr, nullptr,
                                                       0.0f, Hb, n);
    aggregate128_kernel<false><<<ablocks, tb, 0, stream>>>(Hb, offs, csr, dinv, nullptr,
                                                           nullptr, nullptr, 0.0f, Ab, n);
    bn_stats_kernel<<<256, tb, 0, stream>>>(Ab, stats, n);
    // layer 2: BN1+ReLU fused into gemm A-staging
    gemm128_mfma_kernel<1><<<gblocks, tb, 0, stream>>>(Ab, WT2, stats, g1, bt1, invn, Hb, n);
    aggregate128_kernel<false><<<ablocks, tb, 0, stream>>>(Hb, offs, csr, dinv, nullptr,
                                                           nullptr, nullptr, 0.0f, Ab2, n);
    bn_stats_kernel<<<256, tb, 0, stream>>>(Ab2, stats + 256, n);
    // layer 3: BN2+ReLU fused into aggregation gather; then GEMM + fused log_softmax
    aggregate128_kernel<true><<<ablocks, tb, 0, stream>>>(Ab2, offs, csr, dinv, stats + 256,
                                                          g2, bt2, invn, Hb2, n);
    gemm40_lsm_mfma_kernel<<<gblocks, tb, 0, stream>>>(Hb2, WT3, b3, (float*)d_out, n);
}